// Round 3
// baseline (686.893 us; speedup 1.0000x reference)
//
#include <hip/hip_runtime.h>
#include <math.h>

#define NN 50000
#define EE 800000
#define DD 32
#define BSTR 64    // bucket stride (max degree ~45 at Poisson(16); +8 pad fits)
#define NPART 8    // node-range partitions, mapped to XCDs via blockIdx&7
#define CPB 128    // edge chunks per partition (grid = 8*128 = 1024 blocks)

typedef float v2f __attribute__((ext_vector_type(2)));

// ---------------- setup kernels ----------------

__global__ __launch_bounds__(256) void k_zero(float* p, int count){
  int i = blockIdx.x*256 + threadIdx.x;
  if (i < count) p[i] = 0.f;
}

// XCD-partitioned one-pass CSR build (R16-proven: cut write-amp 51->~12 MB).
__global__ __launch_bounds__(256) void k_fillcsr(const int* __restrict__ node_in,
                                                 const int* __restrict__ node_out,
                                                 const float* __restrict__ ew,
                                                 int* __restrict__ cursor,
                                                 int2* __restrict__ csr){
  int part  = blockIdx.x & (NPART-1);
  int group = blockIdx.x >> 3;
  const int per = (EE + CPB - 1) / CPB;   // 6250
  int e0 = group * per;
  int e1 = (e0 + per < EE) ? (e0 + per) : EE;
  unsigned lo = (unsigned)part * 6250u;
  unsigned hi = lo + 6250u;
  for (int e = e0 + threadIdx.x; e < e1; e += 256){
    unsigned o = (unsigned)node_out[e];
    if (o >= lo && o < hi){
      int pos = atomicAdd(&cursor[o], 1);
      int2 v; v.x = node_in[e]; v.y = __float_as_int(ew[e]);
      csr[o*BSTR + pos] = v;
    }
  }
}

// per-node sum(w): 8-lane group per node, coalesced bucket reads, shfl_xor
// reduce; zero the 8-entry pad tail in parallel; block logsum reduce.
__global__ __launch_bounds__(256) void k_sumw(int2* __restrict__ csr,
                                              const int* __restrict__ cursor,
                                              float* __restrict__ deg_w,
                                              float* __restrict__ logsum){
  __shared__ float sf[256];
  int t = threadIdx.x;
  int g = t >> 3, lane = t & 7;
  int n = blockIdx.x*32 + g;
  float s = 0.f;
  if (n < NN){
    int deg = cursor[n];
    int2* row = csr + n*BSTR;
    for (int i = lane; i < deg; i += 8) s += __int_as_float(row[i].y);
    s += __shfl_xor(s, 1);
    s += __shfl_xor(s, 2);
    s += __shfl_xor(s, 4);
    row[deg + lane] = make_int2(0, 0);   // 8 pads, one per lane
    if (lane == 0) deg_w[n] = s;
  }
  sf[t] = (n < NN && lane == 0) ? logf(s + 1.f) : 0.f;
  __syncthreads();
  for (int off = 128; off > 0; off >>= 1){
    if (t < off) sf[t] += sf[t+off];
    __syncthreads();
  }
  if (t == 0) atomicAdd(logsum, sf[0]);
}

// rel_input per layer (6x32), query-part of final MLP (64), and layer-0
// W column-sums over the h-part rows (boundary input is constant per node).
__global__ __launch_bounds__(320) void k_prep(const float* __restrict__ qw,
                                              const float* __restrict__ rel_W,
                                              const float* __restrict__ rel_b,
                                              const float* __restrict__ W1,
                                              const float* __restrict__ b1,
                                              const float* __restrict__ lin_W,
                                              float* __restrict__ rel6,
                                              float* __restrict__ qc,
                                              float* __restrict__ wcol){
  int t = threadIdx.x;
  if (t < 192){
    int l = t >> 5, j = t & 31;
    float s = rel_b[t];
    for (int d = 0; d < 32; ++d) s += qw[d] * rel_W[l*1024 + d*32 + j];
    rel6[t] = s;
  } else if (t < 256){
    int j = t - 192;
    float s = b1[j];
    for (int k = 0; k < 32; ++k) s += qw[k] * W1[(32+k)*64 + j];
    qc[j] = s;
  } else if (t < 288){
    int j = t - 256;
    float s = 0.f;
    for (int k = 0; k < 32; ++k) s += lin_W[k*32 + j];   // layer 0, h-part rows
    wcol[j] = s;
  }
}

// t[n] = dot(h[n], rel_layer5) for msg_score
__global__ __launch_bounds__(256) void k_dot(const float* __restrict__ h,
                                             const float* __restrict__ rel6,
                                             float* __restrict__ tdot){
  int n0 = blockIdx.x*256 + threadIdx.x;
  int n = (n0 < NN) ? n0 : NN-1;
  const float* relr = rel6 + 5*32;
  float s = 0.f;
  #pragma unroll
  for (int d = 0; d < 32; ++d) s += h[n*32 + d] * relr[d];
  if (n0 < NN) tdot[n0] = s;
}

// ---------------- layer 0 (specialized: boundary input) ----------------
// Round-0 structure verbatim (64 nodes / 512 threads / 65-stride LDS).
__global__ __launch_bounds__(512, 6) void k_layer0(const float* __restrict__ rel6,
                                               const int* __restrict__ cursor,
                                               const int2* __restrict__ csr,
                                               const int* __restrict__ hidx,
                                               const float* __restrict__ lin_W,
                                               const float* __restrict__ lin_b,
                                               const float* __restrict__ wcol,
                                               const float* __restrict__ deg_w,
                                               const float* __restrict__ logsum,
                                               float* __restrict__ h_next){
  __shared__ float sh[128*65];
  int tid = threadIdx.x;
  int base = blockIdx.x * 64;
  int hv0 = *hidx;

  // ---- phase 1: scalar aggregation (csr scan only) ----
  {
    int nl   = tid >> 3;
    int quad = tid & 7;
    float4 r4 = ((const float4*)(rel6))[quad];   // layer 0
    int n0 = base + nl;
    int n = (n0 < NN) ? n0 : NN-1;
    int deg = cursor[n];
    int s0 = n*BSTR, s1 = s0 + deg;
    float S1=0.f, S2=0.f, M=-INFINITY, m=INFINITY;

#define ACCS(C) { \
    float w  = __int_as_float(C.y); \
    float hv = (C.x == hv0) ? 0.f : 100.f; \
    float wm = w * hv; \
    S1 += wm; S2 += wm * hv; \
    M = fmaxf(M, wm); m = fminf(m, wm); }

    int2 cA = csr[s0],   cB = csr[s0+1], cC = csr[s0+2], cD = csr[s0+3];
    int e = s0;
    for (; e + 4 <= s1; e += 4){
      int2 nA = csr[e+4], nB = csr[e+5], nC = csr[e+6], nD = csr[e+7];
      ACCS(cA) ACCS(cB) ACCS(cC) ACCS(cD)
      cA = nA; cB = nB; cC = nC; cD = nD;
    }
    if (e < s1){
      ACCS(cA)
      if (e + 1 < s1){
        ACCS(cB)
        if (e + 2 < s1) ACCS(cC)
      }
    }
#undef ACCS

    float bnd = (n == hv0) ? 0.f : 100.f;
    float cntf = (float)(deg + 1);
#define FIN(cc, rc) { \
    float mxv, mnv; \
    if (deg > 0){ \
      float em = (rc >= 0.f) ? rc*M : rc*m; \
      float en = (rc >= 0.f) ? rc*m : rc*M; \
      mxv = fmaxf(em, bnd); mnv = fminf(en, bnd); \
    } else { mxv = bnd; mnv = bnd; } \
    float meanv = (rc*S1 + bnd) / cntf; \
    float sq    = (rc*rc*S2 + bnd*bnd) / cntf; \
    float sdv   = sqrtf(fmaxf(sq - meanv*meanv, 1e-6f)); \
    int d = quad*4 + cc; \
    sh[(d*4+0)*65 + nl] = meanv; \
    sh[(d*4+1)*65 + nl] = mxv; \
    sh[(d*4+2)*65 + nl] = mnv; \
    sh[(d*4+3)*65 + nl] = sdv; }
    FIN(0, r4.x) FIN(1, r4.y) FIN(2, r4.z) FIN(3, r4.w)
#undef FIN
  }
  __syncthreads();

  // ---- phase 2: linear; x-part = bnd * wcol; 3-sum hoist of sc/iv ----
  {
    const float* Wl = lin_W;   // layer 0
    int lane = tid & 63;
    int j0 = __builtin_amdgcn_readfirstlane((tid >> 6) * 4);
    int n0 = base + lane;
    int n = (n0 < NN) ? n0 : NN-1;
    float mean = *logsum / (float)NN;
    float sc = logf(deg_w[n] + 1.f) / mean;
    float iv = 1.f / fmaxf(sc, 0.01f);
    float bndn = (n == hv0) ? 0.f : 100.f;
    v2f a01p={0,0}, a23p={0,0}, a01s={0,0}, a23s={0,0}, a01i={0,0}, a23i={0,0};

    for (int kp = 0; kp < 128; ++kp){
      float f = sh[kp*65 + lane];
      int d = kp >> 2, c = kp & 3;
      const v2f* w2 = (const v2f*)(Wl + (32 + d*12 + c*3)*32 + j0);
      v2f fv; fv[0]=f; fv[1]=f;
      a01p += fv*w2[0];  a23p += fv*w2[1];
      a01s += fv*w2[16]; a23s += fv*w2[17];
      a01i += fv*w2[32]; a23i += fv*w2[33];
    }
    v2f sc2; sc2[0]=sc; sc2[1]=sc;
    v2f iv2; iv2[0]=iv; iv2[1]=iv;
    v2f a01 = a01p + sc2*a01s + iv2*a01i;
    v2f a23 = a23p + sc2*a23s + iv2*a23i;
    a01[0] += lin_b[j0+0] + bndn*wcol[j0+0];
    a01[1] += lin_b[j0+1] + bndn*wcol[j0+1];
    a23[0] += lin_b[j0+2] + bndn*wcol[j0+2];
    a23[1] += lin_b[j0+3] + bndn*wcol[j0+3];

    if (n0 < NN){
      float vs[4] = { a01[0], a01[1], a23[0], a23[1] };
      #pragma unroll
      for (int j = 0; j < 4; ++j)
        h_next[n0*32 + j0 + j] = fmaxf(vs[j], 0.f);
    }
  }
}

// ---------------- fused per-layer kernel (layers 1..5) ----------------
// ROUND-3: full revert to the round-0 (60us) per-lane structure; the ONLY
// change is block geometry: 32 nodes / 256 threads / grid 1563 (was 64/512/
// 782). Rationale: round-0 occupancy 41% was GRID-limited (3.05 blocks/CU)
// with 4-block LDS headroom unused; L3-hit gather latency (~500cy) needs
// TLP. Smaller blocks double resident-wave headroom (8 blocks x 4 waves)
// and halve the __syncthreads imbalance domain. Phase 2: (node,jcol) =
// (tid&31, (tid>>5)*4); LDS stride 65->33 (33 = 1 mod 32 -> 2 lanes/bank,
// free). Cost: weight addrs now half-wave-uniform (no readfirstlane) --
// L1-resident, predicted minor. SW-pipelining of gathers: REJECTED (rounds
// 1-2: spills at (512,6), compiler re-sinks loads at (512,4), both slower).
#define SRO 33
#define PBASE (128*SRO)   // 4224: PRED partial area, 32 nodes x 9
template<bool PRED>
__global__ __launch_bounds__(256, 6) void k_layer(const float* __restrict__ h,
                                               const float* __restrict__ rel6,
                                               const int* __restrict__ cursor,
                                               const int2* __restrict__ csr,
                                               const int* __restrict__ hidx,
                                               const float* __restrict__ tdot,
                                               const float* __restrict__ lin_W,
                                               const float* __restrict__ lin_b,
                                               const float* __restrict__ deg_w,
                                               const float* __restrict__ logsum,
                                               float* __restrict__ h_next,
                                               float* __restrict__ pred_out,
                                               const float* __restrict__ qc,
                                               const float* __restrict__ W1,
                                               const float* __restrict__ W2,
                                               const float* __restrict__ b2,
                                               float* __restrict__ out_score,
                                               int l){
  __shared__ float sh[PBASE + 32*9];   // 18048 B -> 8+ blocks/CU by LDS
  int tid = threadIdx.x;
  int base = blockIdx.x * 32;
  int hv0 = *hidx;

  // ---- phase 1: aggregation (one 8-lane group per node, unroll-4) ----
  // Byte-identical per-lane code to round-0 (60us version).
  {
    int nl   = tid >> 3;     // 0..31
    int quad = tid & 7;
    float4 r4 = ((const float4*)(rel6 + l*32))[quad];
    int n0 = base + nl;
    bool valid = n0 < NN;
    int n = valid ? n0 : NN-1;
    int deg = cursor[n];
    int s0 = n*BSTR, s1 = s0 + deg;
    v2f S1xy={0,0}, S1zw={0,0}, S2xy={0,0}, S2zw={0,0};
    float M0=-INFINITY,M1=-INFINITY,M2=-INFINITY,M3=-INFINITY;
    float m0=INFINITY,m1=INFINITY,m2=INFINITY,m3=INFINITY;
    float best=-INFINITY; int bi=NN;

#define ACC1(C, A, T) { \
    float w = __int_as_float(C.y); \
    v2f wv; wv[0]=w; wv[1]=w; \
    v2f axy; axy[0]=A.x; axy[1]=A.y; \
    v2f azw; azw[0]=A.z; azw[1]=A.w; \
    v2f pxy = wv*axy, pzw = wv*azw; \
    S1xy += pxy; S1zw += pzw; \
    S2xy += pxy*axy; S2zw += pzw*azw; \
    M0=fmaxf(M0,pxy[0]); M1=fmaxf(M1,pxy[1]); M2=fmaxf(M2,pzw[0]); M3=fmaxf(M3,pzw[1]); \
    m0=fminf(m0,pxy[0]); m1=fminf(m1,pxy[1]); m2=fminf(m2,pzw[0]); m3=fminf(m3,pzw[1]); \
    if (PRED){ \
      float sv = w*T; \
      if (sv > best){ best = sv; bi = C.x; } \
      else if (sv == best && C.x < bi) bi = C.x; \
    } }

    int2 cA = csr[s0],   cB = csr[s0+1], cC = csr[s0+2], cD = csr[s0+3];
    int e = s0;
    for (; e + 4 <= s1; e += 4){
      float4 a  = ((const float4*)(h + cA.x*32))[quad];
      float4 b  = ((const float4*)(h + cB.x*32))[quad];
      float4 c4 = ((const float4*)(h + cC.x*32))[quad];
      float4 d4 = ((const float4*)(h + cD.x*32))[quad];
      float tA=0.f, tB=0.f, tC=0.f, tD=0.f;
      if (PRED){ tA = tdot[cA.x]; tB = tdot[cB.x]; tC = tdot[cC.x]; tD = tdot[cD.x]; }
      int2 nA = csr[e+4], nB = csr[e+5], nC = csr[e+6], nD = csr[e+7];
      ACC1(cA, a, tA)
      ACC1(cB, b, tB)
      ACC1(cC, c4, tC)
      ACC1(cD, d4, tD)
      cA = nA; cB = nB; cC = nC; cD = nD;
    }
    if (e < s1){
      float4 a = ((const float4*)(h + cA.x*32))[quad];
      float tA = 0.f; if (PRED) tA = tdot[cA.x];
      ACC1(cA, a, tA)
      if (e + 1 < s1){
        float4 b = ((const float4*)(h + cB.x*32))[quad];
        float tB = 0.f; if (PRED) tB = tdot[cB.x];
        ACC1(cB, b, tB)
        if (e + 2 < s1){
          float4 c4 = ((const float4*)(h + cC.x*32))[quad];
          float tC = 0.f; if (PRED) tC = tdot[cC.x];
          ACC1(cC, c4, tC)
        }
      }
    }
#undef ACC1

    float bnd = (n == hv0) ? 0.f : 100.f;
    float cntf = (float)(deg + 1);
#define FIN(cc, rc, S1c, S2c, Mc, mc) { \
    float mxv, mnv; \
    if (deg > 0){ \
      float em = (rc >= 0.f) ? rc*Mc : rc*mc; \
      float en = (rc >= 0.f) ? rc*mc : rc*Mc; \
      mxv = fmaxf(em, bnd); mnv = fminf(en, bnd); \
    } else { mxv = bnd; mnv = bnd; } \
    float meanv = (rc*S1c + bnd) / cntf; \
    float sq    = (rc*rc*S2c + bnd*bnd) / cntf; \
    float sdv   = sqrtf(fmaxf(sq - meanv*meanv, 1e-6f)); \
    int d = quad*4 + cc; \
    sh[(d*4+0)*SRO + nl] = meanv; \
    sh[(d*4+1)*SRO + nl] = mxv; \
    sh[(d*4+2)*SRO + nl] = mnv; \
    sh[(d*4+3)*SRO + nl] = sdv; }
    FIN(0, r4.x, S1xy[0], S2xy[0], M0, m0)
    FIN(1, r4.y, S1xy[1], S2xy[1], M1, m1)
    FIN(2, r4.z, S1zw[0], S2zw[0], M2, m2)
    FIN(3, r4.w, S1zw[1], S2zw[1], M3, m3)
#undef FIN
    if (PRED && valid && quad == 0){
      float ss = (n == hv0) ? 0.f : 3200.f;   // boundary self-loop row sum, w=1
      if (ss > best){ best = ss; bi = n; }
      else if (ss == best && n < bi) bi = n;
      pred_out[n] = (float)bi;
    }
  }
  __syncthreads();

  // ---- phase 2: linear (thread t -> node = t&31, j0 = (t>>5)*4) ----
  // 3-sum hoist: acc = P + sc*S + iv*I applied once at the end.
  {
    const float* Wl = lin_W + (size_t)l * 13312;
    int node = tid & 31;
    int j0 = (tid >> 5) * 4;            // half-wave-uniform
    int n0 = base + node;
    int n = (n0 < NN) ? n0 : NN-1;
    float mean = *logsum / (float)NN;
    float sc = logf(deg_w[n] + 1.f) / mean;
    float iv = 1.f / fmaxf(sc, 0.01f);
    const float4* hr = (const float4*)(h + (size_t)n*32);
    float4 x0=hr[0],x1=hr[1],x2=hr[2],x3=hr[3],x4=hr[4],x5=hr[5],x6=hr[6],x7=hr[7];
    v2f a01p={0,0}, a23p={0,0}, a01s={0,0}, a23s={0,0}, a01i={0,0}, a23i={0,0};

#define KONE(XV, K) { \
    v2f xv2; xv2[0] = XV; xv2[1] = XV; \
    const v2f* wr2 = (const v2f*)(Wl + (K)*32 + j0); \
    a01p += xv2 * wr2[0]; \
    a23p += xv2 * wr2[1]; }
#define KQ(X, KB) KONE(X.x, KB+0) KONE(X.y, KB+1) KONE(X.z, KB+2) KONE(X.w, KB+3)
    KQ(x0, 0) KQ(x1, 4) KQ(x2, 8) KQ(x3, 12)
    KQ(x4, 16) KQ(x5, 20) KQ(x6, 24) KQ(x7, 28)
#undef KQ
#undef KONE

    for (int kp = 0; kp < 128; ++kp){
      float f = sh[kp*SRO + node];
      int d = kp >> 2, c = kp & 3;
      const v2f* w2 = (const v2f*)(Wl + (32 + d*12 + c*3)*32 + j0);
      v2f fv; fv[0]=f; fv[1]=f;
      a01p += fv*w2[0];  a23p += fv*w2[1];
      a01s += fv*w2[16]; a23s += fv*w2[17];
      a01i += fv*w2[32]; a23i += fv*w2[33];
    }
    v2f sc2; sc2[0]=sc; sc2[1]=sc;
    v2f iv2; iv2[0]=iv; iv2[1]=iv;
    v2f a01 = a01p + sc2*a01s + iv2*a01i;
    v2f a23 = a23p + sc2*a23s + iv2*a23i;
    a01[0] += lin_b[l*32 + j0 + 0];
    a01[1] += lin_b[l*32 + j0 + 1];
    a23[0] += lin_b[l*32 + j0 + 2];
    a23[1] += lin_b[l*32 + j0 + 3];

    float v0r = fmaxf(a01[0], 0.f), v1r = fmaxf(a01[1], 0.f);
    float v2r = fmaxf(a23[0], 0.f), v3r = fmaxf(a23[1], 0.f);

    if (!PRED){
      if (n0 < NN){
        h_next[n0*32 + j0 + 0] = v0r;
        h_next[n0*32 + j0 + 1] = v1r;
        h_next[n0*32 + j0 + 2] = v2r;
        h_next[n0*32 + j0 + 3] = v3r;
      }
    } else {
      // ---- fused final MLP (l=5): h6 never leaves the block ----
      __syncthreads();                    // all phase-2 sh reads complete
      sh[(j0+0)*SRO + node] = v0r;        // stage h6 rows 0..31
      sh[(j0+1)*SRO + node] = v1r;
      sh[(j0+2)*SRO + node] = v2r;
      sh[(j0+3)*SRO + node] = v3r;
      __syncthreads();
      int nd2 = tid & 31;
      int hg  = tid >> 5;                 // 0..7
      int jm = hg*8;
      v2f b0, b1v, b2v, b3;
      b0[0]=qc[jm+0]; b0[1]=qc[jm+1]; b1v[0]=qc[jm+2]; b1v[1]=qc[jm+3];
      b2v[0]=qc[jm+4]; b2v[1]=qc[jm+5]; b3[0]=qc[jm+6]; b3[1]=qc[jm+7];
      for (int k = 0; k < 32; ++k){
        float xv = sh[k*SRO + nd2];
        const v2f* wr = (const v2f*)(W1 + k*64 + jm);
        v2f xv2; xv2[0]=xv; xv2[1]=xv;
        b0 += xv2*wr[0]; b1v += xv2*wr[1]; b2v += xv2*wr[2]; b3 += xv2*wr[3];
      }
      float part = fmaxf(b0[0],0.f)*W2[jm+0] + fmaxf(b0[1],0.f)*W2[jm+1]
                 + fmaxf(b1v[0],0.f)*W2[jm+2] + fmaxf(b1v[1],0.f)*W2[jm+3]
                 + fmaxf(b2v[0],0.f)*W2[jm+4] + fmaxf(b2v[1],0.f)*W2[jm+5]
                 + fmaxf(b3[0],0.f)*W2[jm+6] + fmaxf(b3[1],0.f)*W2[jm+7];
      sh[PBASE + nd2*9 + hg] = part;
      __syncthreads();
      if (tid < 32){
        float s = b2[0];
        #pragma unroll
        for (int g = 0; g < 8; ++g) s += sh[PBASE + tid*9 + g];
        if (base + tid < NN) out_score[base + tid] = s;
      }
    }
  }
}

// ---------------- host launch ----------------
extern "C" void kernel_launch(void* const* d_in, const int* in_sizes, int n_in,
                              void* d_out, int out_size, void* d_ws, size_t ws_size,
                              hipStream_t stream){
  const int*   node_in  = (const int*)d_in[0];
  const int*   node_out = (const int*)d_in[1];
  const float* ew       = (const float*)d_in[2];
  const int*   hidx     = (const int*)d_in[3];
  const float* qw       = (const float*)d_in[4];
  const float* rel_W    = (const float*)d_in[5];
  const float* rel_b    = (const float*)d_in[6];
  const float* lin_W    = (const float*)d_in[7];
  const float* lin_b    = (const float*)d_in[8];
  const float* W1       = (const float*)d_in[9];
  const float* b1       = (const float*)d_in[10];
  const float* W2       = (const float*)d_in[11];
  const float* b2       = (const float*)d_in[12];
  float* out_score = (float*)d_out;
  float* out_pred  = out_score + NN;

  char* w = (char*)d_ws;
  size_t off = 0;
  auto take = [&](size_t bytes)->char*{
    char* p = w + off;
    off = (off + bytes + 255) & ~(size_t)255;
    return p;
  };
  size_t bucket_elems = (size_t)NN * BSTR;            // int2 entries
  int2*  csr      = (int2*)take(bucket_elems*8);
  // contiguous zero block: cursor | deg_w | logsum
  char*  zb       = take((size_t)NN*4 + (size_t)NN*4 + 256);
  int*   cursor   = (int*)zb;
  float* deg_w    = (float*)(cursor + NN);
  float* logsum   = (float*)(deg_w + NN);
  int zc = NN + NN + 64;

  float* rel6      = (float*)take(192*4);
  float* qc        = (float*)take(64*4);
  float* wcol      = (float*)take(32*4);
  float* tdot      = (float*)take((size_t)NN*4);
  float* h_a       = (float*)take((size_t)NN*32*4);
  float* h_b       = (float*)take((size_t)NN*32*4);

  int nb   = (NN + 255) / 256;   // 196
  int nsb  = (NN + 31) / 32;     // 1563 (k_sumw: 32 nodes/block)
  int nlb  = (NN + 63) / 64;     // 782  (k_layer0: 64 nodes/block)
  int nlb2 = (NN + 31) / 32;     // 1563 (k_layer: 32 nodes/block)
  k_zero   <<<(zc+255)/256, 256, 0, stream>>>((float*)zb, zc);
  k_fillcsr<<<NPART*CPB, 256, 0, stream>>>(node_in, node_out, ew, cursor, csr);
  k_sumw   <<<nsb, 256, 0, stream>>>(csr, cursor, deg_w, logsum);
  k_prep   <<<1, 320, 0, stream>>>(qw, rel_W, rel_b, W1, b1, lin_W, rel6, qc, wcol);

  // layer 0 (specialized, no h input)
  k_layer0<<<nlb, 512, 0, stream>>>(rel6, cursor, csr, hidx, lin_W, lin_b,
                                    wcol, deg_w, logsum, h_a);

  float* hc = h_a;
  float* hn = h_b;
  for (int l = 1; l < 6; ++l){
    if (l == 5){
      k_dot<<<nb, 256, 0, stream>>>(hc, rel6, tdot);
      k_layer<true><<<nlb2, 256, 0, stream>>>(hc, rel6, cursor, csr, hidx, tdot,
                                              lin_W, lin_b, deg_w, logsum,
                                              hn, out_pred,
                                              qc, W1, W2, b2, out_score, l);
    } else {
      k_layer<false><<<nlb2, 256, 0, stream>>>(hc, rel6, cursor, csr, hidx, tdot,
                                               lin_W, lin_b, deg_w, logsum,
                                               hn, out_pred,
                                               qc, W1, W2, b2, out_score, l);
    }
    float* t1 = hc; hc = hn; hn = t1;
  }
}

// Round 4
// 522.952 us; speedup vs baseline: 1.3135x; 1.3135x over previous
//
#include <hip/hip_runtime.h>
#include <math.h>

#define NN 50000
#define EE 800000
#define DD 32
#define BSTR 64    // bucket stride (max degree ~45 at Poisson(16); +8 pad fits)
#define NPART 8    // node-range partitions, mapped to XCDs via blockIdx&7
#define CPB 128    // edge chunks per partition (grid = 8*128 = 1024 blocks)

typedef float v2f __attribute__((ext_vector_type(2)));

// ---------------- setup kernels ----------------

__global__ __launch_bounds__(256) void k_zero(float* p, int count){
  int i = blockIdx.x*256 + threadIdx.x;
  if (i < count) p[i] = 0.f;
}

// XCD-partitioned one-pass CSR build (R16-proven: cut write-amp 51->~12 MB).
__global__ __launch_bounds__(256) void k_fillcsr(const int* __restrict__ node_in,
                                                 const int* __restrict__ node_out,
                                                 const float* __restrict__ ew,
                                                 int* __restrict__ cursor,
                                                 int2* __restrict__ csr){
  int part  = blockIdx.x & (NPART-1);
  int group = blockIdx.x >> 3;
  const int per = (EE + CPB - 1) / CPB;   // 6250
  int e0 = group * per;
  int e1 = (e0 + per < EE) ? (e0 + per) : EE;
  unsigned lo = (unsigned)part * 6250u;
  unsigned hi = lo + 6250u;
  for (int e = e0 + threadIdx.x; e < e1; e += 256){
    unsigned o = (unsigned)node_out[e];
    if (o >= lo && o < hi){
      int pos = atomicAdd(&cursor[o], 1);
      int2 v; v.x = node_in[e]; v.y = __float_as_int(ew[e]);
      csr[o*BSTR + pos] = v;
    }
  }
}

// per-node sum(w): 8-lane group per node, coalesced bucket reads, shfl_xor
// reduce; zero the 8-entry pad tail in parallel; block logsum reduce.
__global__ __launch_bounds__(256) void k_sumw(int2* __restrict__ csr,
                                              const int* __restrict__ cursor,
                                              float* __restrict__ deg_w,
                                              float* __restrict__ logsum){
  __shared__ float sf[256];
  int t = threadIdx.x;
  int g = t >> 3, lane = t & 7;
  int n = blockIdx.x*32 + g;
  float s = 0.f;
  if (n < NN){
    int deg = cursor[n];
    int2* row = csr + n*BSTR;
    for (int i = lane; i < deg; i += 8) s += __int_as_float(row[i].y);
    s += __shfl_xor(s, 1);
    s += __shfl_xor(s, 2);
    s += __shfl_xor(s, 4);
    row[deg + lane] = make_int2(0, 0);   // 8 pads, one per lane
    if (lane == 0) deg_w[n] = s;
  }
  sf[t] = (n < NN && lane == 0) ? logf(s + 1.f) : 0.f;
  __syncthreads();
  for (int off = 128; off > 0; off >>= 1){
    if (t < off) sf[t] += sf[t+off];
    __syncthreads();
  }
  if (t == 0) atomicAdd(logsum, sf[0]);
}

// rel_input per layer (6x32), query-part of final MLP (64), and layer-0
// W column-sums over the h-part rows (boundary input is constant per node).
__global__ __launch_bounds__(320) void k_prep(const float* __restrict__ qw,
                                              const float* __restrict__ rel_W,
                                              const float* __restrict__ rel_b,
                                              const float* __restrict__ W1,
                                              const float* __restrict__ b1,
                                              const float* __restrict__ lin_W,
                                              float* __restrict__ rel6,
                                              float* __restrict__ qc,
                                              float* __restrict__ wcol){
  int t = threadIdx.x;
  if (t < 192){
    int l = t >> 5, j = t & 31;
    float s = rel_b[t];
    for (int d = 0; d < 32; ++d) s += qw[d] * rel_W[l*1024 + d*32 + j];
    rel6[t] = s;
  } else if (t < 256){
    int j = t - 192;
    float s = b1[j];
    for (int k = 0; k < 32; ++k) s += qw[k] * W1[(32+k)*64 + j];
    qc[j] = s;
  } else if (t < 288){
    int j = t - 256;
    float s = 0.f;
    for (int k = 0; k < 32; ++k) s += lin_W[k*32 + j];   // layer 0, h-part rows
    wcol[j] = s;
  }
}

// t[n] = dot(h[n], rel_layer5) for msg_score
__global__ __launch_bounds__(256) void k_dot(const float* __restrict__ h,
                                             const float* __restrict__ rel6,
                                             float* __restrict__ tdot){
  int n0 = blockIdx.x*256 + threadIdx.x;
  int n = (n0 < NN) ? n0 : NN-1;
  const float* relr = rel6 + 5*32;
  float s = 0.f;
  #pragma unroll
  for (int d = 0; d < 32; ++d) s += h[n*32 + d] * relr[d];
  if (n0 < NN) tdot[n0] = s;
}

// ROUND-4: round-0 structure (512 thr / 64 nodes / (512,6) / readfirstlane
// j0 / original non-pipelined phase-1) + ONLY the phase-2 LDS transpose,
// isolated: feats stored sh[node][feat] (stride 132) so phase 2 reads its
// 128 feats as 32 x ds_read_b128 (4x fewer LDS ops, clustered -> fewer
// lgkmcnt drains against the s_load weight stream). Stride 132 words ->
// b128 reads tile all 32 banks uniformly (8 words/bank = hw floor).
// Accumulation order preserved exactly (channel-major, stat-minor).
// Rejected levers (counter-proven): SW-pipelined gathers (r1 spill: WRITE
// 0.4->17.6MB; r2 compiler re-sink at (512,4)); smaller blocks (r3:
// occupancy pinned 41%, and non-wave-uniform j0 loses s_loads -> 2x).
#define SROW 132

// ---------------- layer 0 (specialized: boundary input) ----------------
__global__ __launch_bounds__(512, 6) void k_layer0(const float* __restrict__ rel6,
                                               const int* __restrict__ cursor,
                                               const int2* __restrict__ csr,
                                               const int* __restrict__ hidx,
                                               const float* __restrict__ lin_W,
                                               const float* __restrict__ lin_b,
                                               const float* __restrict__ wcol,
                                               const float* __restrict__ deg_w,
                                               const float* __restrict__ logsum,
                                               float* __restrict__ h_next){
  __shared__ __align__(16) float sh[64*SROW];
  int tid = threadIdx.x;
  int base = blockIdx.x * 64;
  int hv0 = *hidx;

  // ---- phase 1: scalar aggregation (csr scan only) ----
  {
    int nl   = tid >> 3;
    int quad = tid & 7;
    float4 r4 = ((const float4*)(rel6))[quad];   // layer 0
    int n0 = base + nl;
    int n = (n0 < NN) ? n0 : NN-1;
    int deg = cursor[n];
    int s0 = n*BSTR, s1 = s0 + deg;
    float S1=0.f, S2=0.f, M=-INFINITY, m=INFINITY;

#define ACCS(C) { \
    float w  = __int_as_float(C.y); \
    float hv = (C.x == hv0) ? 0.f : 100.f; \
    float wm = w * hv; \
    S1 += wm; S2 += wm * hv; \
    M = fmaxf(M, wm); m = fminf(m, wm); }

    int2 cA = csr[s0],   cB = csr[s0+1], cC = csr[s0+2], cD = csr[s0+3];
    int e = s0;
    for (; e + 4 <= s1; e += 4){
      int2 nA = csr[e+4], nB = csr[e+5], nC = csr[e+6], nD = csr[e+7];
      ACCS(cA) ACCS(cB) ACCS(cC) ACCS(cD)
      cA = nA; cB = nB; cC = nC; cD = nD;
    }
    if (e < s1){
      ACCS(cA)
      if (e + 1 < s1){
        ACCS(cB)
        if (e + 2 < s1) ACCS(cC)
      }
    }
#undef ACCS

    float bnd = (n == hv0) ? 0.f : 100.f;
    float cntf = (float)(deg + 1);
#define FIN(cc, rc) { \
    float mxv, mnv; \
    if (deg > 0){ \
      float em = (rc >= 0.f) ? rc*M : rc*m; \
      float en = (rc >= 0.f) ? rc*m : rc*M; \
      mxv = fmaxf(em, bnd); mnv = fminf(en, bnd); \
    } else { mxv = bnd; mnv = bnd; } \
    float meanv = (rc*S1 + bnd) / cntf; \
    float sq    = (rc*rc*S2 + bnd*bnd) / cntf; \
    float sdv   = sqrtf(fmaxf(sq - meanv*meanv, 1e-6f)); \
    int d = quad*4 + cc; \
    float4 o; o.x = meanv; o.y = mxv; o.z = mnv; o.w = sdv; \
    *(float4*)(sh + nl*SROW + d*4) = o; }
    FIN(0, r4.x) FIN(1, r4.y) FIN(2, r4.z) FIN(3, r4.w)
#undef FIN
  }
  __syncthreads();

  // ---- phase 2: linear; x-part = bnd * wcol; 3-sum hoist of sc/iv ----
  {
    const float* Wl = lin_W;   // layer 0
    int lane = tid & 63;
    int j0 = __builtin_amdgcn_readfirstlane((tid >> 6) * 4);
    int n0 = base + lane;
    int n = (n0 < NN) ? n0 : NN-1;
    float mean = *logsum / (float)NN;
    float sc = logf(deg_w[n] + 1.f) / mean;
    float iv = 1.f / fmaxf(sc, 0.01f);
    float bndn = (n == hv0) ? 0.f : 100.f;
    v2f a01p={0,0}, a23p={0,0}, a01s={0,0}, a23s={0,0}, a01i={0,0}, a23i={0,0};

#define CSTAT(dd, cc, fv) { \
    const v2f* w2 = (const v2f*)(Wl + (32 + (dd)*12 + (cc)*3)*32 + j0); \
    v2f fvv; fvv[0]=(fv); fvv[1]=(fv); \
    a01p += fvv*w2[0];  a23p += fvv*w2[1]; \
    a01s += fvv*w2[16]; a23s += fvv*w2[17]; \
    a01i += fvv*w2[32]; a23i += fvv*w2[33]; }

    const float4* frow = (const float4*)(sh + lane*SROW);
    for (int d = 0; d < 32; d += 4){
      float4 fa = frow[d], fb = frow[d+1], fc = frow[d+2], fd = frow[d+3];
      CSTAT(d+0,0,fa.x) CSTAT(d+0,1,fa.y) CSTAT(d+0,2,fa.z) CSTAT(d+0,3,fa.w)
      CSTAT(d+1,0,fb.x) CSTAT(d+1,1,fb.y) CSTAT(d+1,2,fb.z) CSTAT(d+1,3,fb.w)
      CSTAT(d+2,0,fc.x) CSTAT(d+2,1,fc.y) CSTAT(d+2,2,fc.z) CSTAT(d+2,3,fc.w)
      CSTAT(d+3,0,fd.x) CSTAT(d+3,1,fd.y) CSTAT(d+3,2,fd.z) CSTAT(d+3,3,fd.w)
    }
    v2f sc2; sc2[0]=sc; sc2[1]=sc;
    v2f iv2; iv2[0]=iv; iv2[1]=iv;
    v2f a01 = a01p + sc2*a01s + iv2*a01i;
    v2f a23 = a23p + sc2*a23s + iv2*a23i;
    a01[0] += lin_b[j0+0] + bndn*wcol[j0+0];
    a01[1] += lin_b[j0+1] + bndn*wcol[j0+1];
    a23[0] += lin_b[j0+2] + bndn*wcol[j0+2];
    a23[1] += lin_b[j0+3] + bndn*wcol[j0+3];

    if (n0 < NN){
      float vs[4] = { a01[0], a01[1], a23[0], a23[1] };
      #pragma unroll
      for (int j = 0; j < 4; ++j)
        h_next[n0*32 + j0 + j] = fmaxf(vs[j], 0.f);
    }
  }
}

// ---------------- fused per-layer kernel (layers 1..5) ----------------
// Phase 1: round-0 loop verbatim (csr one-ahead prefetch, gathers consumed
// in-iteration -- compiler schedules this best; see rejected levers above).
// Phase 2: transposed-LDS b128 reads. PRED (l=5): predecessor tracking in
// phase 1, final MLP fused in the epilogue (65-stride staging area, as r0).
template<bool PRED>
__global__ __launch_bounds__(512, 6) void k_layer(const float* __restrict__ h,
                                               const float* __restrict__ rel6,
                                               const int* __restrict__ cursor,
                                               const int2* __restrict__ csr,
                                               const int* __restrict__ hidx,
                                               const float* __restrict__ tdot,
                                               const float* __restrict__ lin_W,
                                               const float* __restrict__ lin_b,
                                               const float* __restrict__ deg_w,
                                               const float* __restrict__ logsum,
                                               float* __restrict__ h_next,
                                               float* __restrict__ pred_out,
                                               const float* __restrict__ qc,
                                               const float* __restrict__ W1,
                                               const float* __restrict__ W2,
                                               const float* __restrict__ b2,
                                               float* __restrict__ out_score,
                                               int l){
  __shared__ __align__(16) float sh[64*SROW];
  int tid = threadIdx.x;
  int base = blockIdx.x * 64;
  int hv0 = *hidx;

  // ---- phase 1: aggregation (one 8-lane group per node, unroll-4) ----
  {
    int nl   = tid >> 3;
    int quad = tid & 7;
    float4 r4 = ((const float4*)(rel6 + l*32))[quad];
    int n0 = base + nl;
    bool valid = n0 < NN;
    int n = valid ? n0 : NN-1;
    int deg = cursor[n];
    int s0 = n*BSTR, s1 = s0 + deg;
    v2f S1xy={0,0}, S1zw={0,0}, S2xy={0,0}, S2zw={0,0};
    float M0=-INFINITY,M1=-INFINITY,M2=-INFINITY,M3=-INFINITY;
    float m0=INFINITY,m1=INFINITY,m2=INFINITY,m3=INFINITY;
    float best=-INFINITY; int bi=NN;

#define ACC1(C, A, T) { \
    float w = __int_as_float(C.y); \
    v2f wv; wv[0]=w; wv[1]=w; \
    v2f axy; axy[0]=A.x; axy[1]=A.y; \
    v2f azw; azw[0]=A.z; azw[1]=A.w; \
    v2f pxy = wv*axy, pzw = wv*azw; \
    S1xy += pxy; S1zw += pzw; \
    S2xy += pxy*axy; S2zw += pzw*azw; \
    M0=fmaxf(M0,pxy[0]); M1=fmaxf(M1,pxy[1]); M2=fmaxf(M2,pzw[0]); M3=fmaxf(M3,pzw[1]); \
    m0=fminf(m0,pxy[0]); m1=fminf(m1,pxy[1]); m2=fminf(m2,pzw[0]); m3=fminf(m3,pzw[1]); \
    if (PRED){ \
      float sv = w*T; \
      if (sv > best){ best = sv; bi = C.x; } \
      else if (sv == best && C.x < bi) bi = C.x; \
    } }

    int2 cA = csr[s0],   cB = csr[s0+1], cC = csr[s0+2], cD = csr[s0+3];
    int e = s0;
    for (; e + 4 <= s1; e += 4){
      float4 a  = ((const float4*)(h + cA.x*32))[quad];
      float4 b  = ((const float4*)(h + cB.x*32))[quad];
      float4 c4 = ((const float4*)(h + cC.x*32))[quad];
      float4 d4 = ((const float4*)(h + cD.x*32))[quad];
      float tA=0.f, tB=0.f, tC=0.f, tD=0.f;
      if (PRED){ tA = tdot[cA.x]; tB = tdot[cB.x]; tC = tdot[cC.x]; tD = tdot[cD.x]; }
      int2 nA = csr[e+4], nB = csr[e+5], nC = csr[e+6], nD = csr[e+7];
      ACC1(cA, a, tA)
      ACC1(cB, b, tB)
      ACC1(cC, c4, tC)
      ACC1(cD, d4, tD)
      cA = nA; cB = nB; cC = nC; cD = nD;
    }
    if (e < s1){
      float4 a = ((const float4*)(h + cA.x*32))[quad];
      float tA = 0.f; if (PRED) tA = tdot[cA.x];
      ACC1(cA, a, tA)
      if (e + 1 < s1){
        float4 b = ((const float4*)(h + cB.x*32))[quad];
        float tB = 0.f; if (PRED) tB = tdot[cB.x];
        ACC1(cB, b, tB)
        if (e + 2 < s1){
          float4 c4 = ((const float4*)(h + cC.x*32))[quad];
          float tC = 0.f; if (PRED) tC = tdot[cC.x];
          ACC1(cC, c4, tC)
        }
      }
    }
#undef ACC1

    float bnd = (n == hv0) ? 0.f : 100.f;
    float cntf = (float)(deg + 1);
#define FIN(cc, rc, S1c, S2c, Mc, mc) { \
    float mxv, mnv; \
    if (deg > 0){ \
      float em = (rc >= 0.f) ? rc*Mc : rc*mc; \
      float en = (rc >= 0.f) ? rc*mc : rc*Mc; \
      mxv = fmaxf(em, bnd); mnv = fminf(en, bnd); \
    } else { mxv = bnd; mnv = bnd; } \
    float meanv = (rc*S1c + bnd) / cntf; \
    float sq    = (rc*rc*S2c + bnd*bnd) / cntf; \
    float sdv   = sqrtf(fmaxf(sq - meanv*meanv, 1e-6f)); \
    int d = quad*4 + cc; \
    float4 o; o.x = meanv; o.y = mxv; o.z = mnv; o.w = sdv; \
    *(float4*)(sh + nl*SROW + d*4) = o; }
    FIN(0, r4.x, S1xy[0], S2xy[0], M0, m0)
    FIN(1, r4.y, S1xy[1], S2xy[1], M1, m1)
    FIN(2, r4.z, S1zw[0], S2zw[0], M2, m2)
    FIN(3, r4.w, S1zw[1], S2zw[1], M3, m3)
#undef FIN
    if (PRED && valid && quad == 0){
      float ss = (n == hv0) ? 0.f : 3200.f;   // boundary self-loop row sum, w=1
      if (ss > best){ best = ss; bi = n; }
      else if (ss == best && n < bi) bi = n;
      pred_out[n] = (float)bi;
    }
  }
  __syncthreads();

  // ---- phase 2: linear (8 waves, wave w -> j0 = w*4; node = lane) ----
  // 3-sum hoist: acc = P + sc*S + iv*I applied once at the end.
  {
    const float* Wl = lin_W + (size_t)l * 13312;
    int lane = tid & 63;
    int j0 = __builtin_amdgcn_readfirstlane((tid >> 6) * 4);
    int n0 = base + lane;
    int n = (n0 < NN) ? n0 : NN-1;
    float mean = *logsum / (float)NN;
    float sc = logf(deg_w[n] + 1.f) / mean;
    float iv = 1.f / fmaxf(sc, 0.01f);
    const float4* hr = (const float4*)(h + (size_t)n*32);
    float4 x0=hr[0],x1=hr[1],x2=hr[2],x3=hr[3],x4=hr[4],x5=hr[5],x6=hr[6],x7=hr[7];
    v2f a01p={0,0}, a23p={0,0}, a01s={0,0}, a23s={0,0}, a01i={0,0}, a23i={0,0};

#define KONE(XV, K) { \
    v2f xv2; xv2[0] = XV; xv2[1] = XV; \
    const v2f* wr2 = (const v2f*)(Wl + (K)*32 + j0); \
    a01p += xv2 * wr2[0]; \
    a23p += xv2 * wr2[1]; }
#define KQ(X, KB) KONE(X.x, KB+0) KONE(X.y, KB+1) KONE(X.z, KB+2) KONE(X.w, KB+3)
    KQ(x0, 0) KQ(x1, 4) KQ(x2, 8) KQ(x3, 12)
    KQ(x4, 16) KQ(x5, 20) KQ(x6, 24) KQ(x7, 28)
#undef KQ
#undef KONE

    const float4* frow = (const float4*)(sh + lane*SROW);
    for (int d = 0; d < 32; d += 4){
      float4 fa = frow[d], fb = frow[d+1], fc = frow[d+2], fd = frow[d+3];
      CSTAT(d+0,0,fa.x) CSTAT(d+0,1,fa.y) CSTAT(d+0,2,fa.z) CSTAT(d+0,3,fa.w)
      CSTAT(d+1,0,fb.x) CSTAT(d+1,1,fb.y) CSTAT(d+1,2,fb.z) CSTAT(d+1,3,fb.w)
      CSTAT(d+2,0,fc.x) CSTAT(d+2,1,fc.y) CSTAT(d+2,2,fc.z) CSTAT(d+2,3,fc.w)
      CSTAT(d+3,0,fd.x) CSTAT(d+3,1,fd.y) CSTAT(d+3,2,fd.z) CSTAT(d+3,3,fd.w)
    }
    v2f sc2; sc2[0]=sc; sc2[1]=sc;
    v2f iv2; iv2[0]=iv; iv2[1]=iv;
    v2f a01 = a01p + sc2*a01s + iv2*a01i;
    v2f a23 = a23p + sc2*a23s + iv2*a23i;
    a01[0] += lin_b[l*32 + j0 + 0];
    a01[1] += lin_b[l*32 + j0 + 1];
    a23[0] += lin_b[l*32 + j0 + 2];
    a23[1] += lin_b[l*32 + j0 + 3];

    float v0r = fmaxf(a01[0], 0.f), v1r = fmaxf(a01[1], 0.f);
    float v2r = fmaxf(a23[0], 0.f), v3r = fmaxf(a23[1], 0.f);

    if (!PRED){
      if (n0 < NN){
        h_next[n0*32 + j0 + 0] = v0r;
        h_next[n0*32 + j0 + 1] = v1r;
        h_next[n0*32 + j0 + 2] = v2r;
        h_next[n0*32 + j0 + 3] = v3r;
      }
    } else {
      // ---- fused final MLP (l=5): h6 never leaves the block ----
      __syncthreads();                    // all phase-2 sh reads complete
      sh[(j0+0)*65 + lane] = v0r;         // stage h6 rows 0..31 (65-stride)
      sh[(j0+1)*65 + lane] = v1r;
      sh[(j0+2)*65 + lane] = v2r;
      sh[(j0+3)*65 + lane] = v3r;
      __syncthreads();
      int node = tid & 63;
      int grp  = __builtin_amdgcn_readfirstlane(tid >> 6);   // 0..7
      int jm = grp*8;                     // wave-uniform -> W1 s_loads
      v2f b0, b1v, b2v, b3;
      b0[0]=qc[jm+0]; b0[1]=qc[jm+1]; b1v[0]=qc[jm+2]; b1v[1]=qc[jm+3];
      b2v[0]=qc[jm+4]; b2v[1]=qc[jm+5]; b3[0]=qc[jm+6]; b3[1]=qc[jm+7];
      for (int k = 0; k < 32; ++k){
        float xv = sh[k*65 + node];
        const v2f* wr = (const v2f*)(W1 + k*64 + jm);
        v2f xv2; xv2[0]=xv; xv2[1]=xv;
        b0 += xv2*wr[0]; b1v += xv2*wr[1]; b2v += xv2*wr[2]; b3 += xv2*wr[3];
      }
      float part = fmaxf(b0[0],0.f)*W2[jm+0] + fmaxf(b0[1],0.f)*W2[jm+1]
                 + fmaxf(b1v[0],0.f)*W2[jm+2] + fmaxf(b1v[1],0.f)*W2[jm+3]
                 + fmaxf(b2v[0],0.f)*W2[jm+4] + fmaxf(b2v[1],0.f)*W2[jm+5]
                 + fmaxf(b3[0],0.f)*W2[jm+6] + fmaxf(b3[1],0.f)*W2[jm+7];
      sh[2080 + node*9 + grp] = part;     // past the 32 staged rows (2080)
      __syncthreads();
      if (tid < 64){
        float s = b2[0];
        #pragma unroll
        for (int g = 0; g < 8; ++g) s += sh[2080 + tid*9 + g];
        if (base + tid < NN) out_score[base + tid] = s;
      }
    }
  }
}

// ---------------- host launch ----------------
extern "C" void kernel_launch(void* const* d_in, const int* in_sizes, int n_in,
                              void* d_out, int out_size, void* d_ws, size_t ws_size,
                              hipStream_t stream){
  const int*   node_in  = (const int*)d_in[0];
  const int*   node_out = (const int*)d_in[1];
  const float* ew       = (const float*)d_in[2];
  const int*   hidx     = (const int*)d_in[3];
  const float* qw       = (const float*)d_in[4];
  const float* rel_W    = (const float*)d_in[5];
  const float* rel_b    = (const float*)d_in[6];
  const float* lin_W    = (const float*)d_in[7];
  const float* lin_b    = (const float*)d_in[8];
  const float* W1       = (const float*)d_in[9];
  const float* b1       = (const float*)d_in[10];
  const float* W2       = (const float*)d_in[11];
  const float* b2       = (const float*)d_in[12];
  float* out_score = (float*)d_out;
  float* out_pred  = out_score + NN;

  char* w = (char*)d_ws;
  size_t off = 0;
  auto take = [&](size_t bytes)->char*{
    char* p = w + off;
    off = (off + bytes + 255) & ~(size_t)255;
    return p;
  };
  size_t bucket_elems = (size_t)NN * BSTR;            // int2 entries
  int2*  csr      = (int2*)take(bucket_elems*8);
  // contiguous zero block: cursor | deg_w | logsum
  char*  zb       = take((size_t)NN*4 + (size_t)NN*4 + 256);
  int*   cursor   = (int*)zb;
  float* deg_w    = (float*)(cursor + NN);
  float* logsum   = (float*)(deg_w + NN);
  int zc = NN + NN + 64;

  float* rel6      = (float*)take(192*4);
  float* qc        = (float*)take(64*4);
  float* wcol      = (float*)take(32*4);
  float* tdot      = (float*)take((size_t)NN*4);
  float* h_a       = (float*)take((size_t)NN*32*4);
  float* h_b       = (float*)take((size_t)NN*32*4);

  int nb  = (NN + 255) / 256;   // 196
  int nsb = (NN + 31) / 32;     // 1563 (k_sumw: 32 nodes/block)
  int nlb = (NN + 63) / 64;     // 782
  k_zero   <<<(zc+255)/256, 256, 0, stream>>>((float*)zb, zc);
  k_fillcsr<<<NPART*CPB, 256, 0, stream>>>(node_in, node_out, ew, cursor, csr);
  k_sumw   <<<nsb, 256, 0, stream>>>(csr, cursor, deg_w, logsum);
  k_prep   <<<1, 320, 0, stream>>>(qw, rel_W, rel_b, W1, b1, lin_W, rel6, qc, wcol);

  // layer 0 (specialized, no h input)
  k_layer0<<<nlb, 512, 0, stream>>>(rel6, cursor, csr, hidx, lin_W, lin_b,
                                    wcol, deg_w, logsum, h_a);

  float* hc = h_a;
  float* hn = h_b;
  for (int l = 1; l < 6; ++l){
    if (l == 5){
      k_dot<<<nb, 256, 0, stream>>>(hc, rel6, tdot);
      k_layer<true><<<nlb, 512, 0, stream>>>(hc, rel6, cursor, csr, hidx, tdot,
                                             lin_W, lin_b, deg_w, logsum,
                                             hn, out_pred,
                                             qc, W1, W2, b2, out_score, l);
    } else {
      k_layer<false><<<nlb, 512, 0, stream>>>(hc, rel6, cursor, csr, hidx, tdot,
                                              lin_W, lin_b, deg_w, logsum,
                                              hn, out_pred,
                                              qc, W1, W2, b2, out_score, l);
    }
    float* t1 = hc; hc = hn; hn = t1;
  }
}

// Round 5
// 379.367 us; speedup vs baseline: 1.8106x; 1.3785x over previous
//
#include <hip/hip_runtime.h>
#include <math.h>

#define NN 50000
#define EE 800000
#define DD 32
#define BSTR 64    // bucket stride (max degree ~45 at Poisson(16); +8 pad fits)
#define NPART 8    // node-range partitions, mapped to XCDs via blockIdx&7
#define CPB 128    // edge chunks per partition (grid = 8*128 = 1024 blocks)

typedef float v2f __attribute__((ext_vector_type(2)));

// ---------------- setup kernels ----------------

__global__ __launch_bounds__(256) void k_zero(float* p, int count){
  int i = blockIdx.x*256 + threadIdx.x;
  if (i < count) p[i] = 0.f;
}

// XCD-partitioned one-pass CSR build (R16-proven: cut write-amp 51->~12 MB).
__global__ __launch_bounds__(256) void k_fillcsr(const int* __restrict__ node_in,
                                                 const int* __restrict__ node_out,
                                                 const float* __restrict__ ew,
                                                 int* __restrict__ cursor,
                                                 int2* __restrict__ csr){
  int part  = blockIdx.x & (NPART-1);
  int group = blockIdx.x >> 3;
  const int per = (EE + CPB - 1) / CPB;   // 6250
  int e0 = group * per;
  int e1 = (e0 + per < EE) ? (e0 + per) : EE;
  unsigned lo = (unsigned)part * 6250u;
  unsigned hi = lo + 6250u;
  for (int e = e0 + threadIdx.x; e < e1; e += 256){
    unsigned o = (unsigned)node_out[e];
    if (o >= lo && o < hi){
      int pos = atomicAdd(&cursor[o], 1);
      int2 v; v.x = node_in[e]; v.y = __float_as_int(ew[e]);
      csr[o*BSTR + pos] = v;
    }
  }
}

// per-node sum(w): 8-lane group per node, coalesced bucket reads, shfl_xor
// reduce; zero the 8-entry pad tail in parallel; block logsum reduce.
__global__ __launch_bounds__(256) void k_sumw(int2* __restrict__ csr,
                                              const int* __restrict__ cursor,
                                              float* __restrict__ deg_w,
                                              float* __restrict__ logsum){
  __shared__ float sf[256];
  int t = threadIdx.x;
  int g = t >> 3, lane = t & 7;
  int n = blockIdx.x*32 + g;
  float s = 0.f;
  if (n < NN){
    int deg = cursor[n];
    int2* row = csr + n*BSTR;
    for (int i = lane; i < deg; i += 8) s += __int_as_float(row[i].y);
    s += __shfl_xor(s, 1);
    s += __shfl_xor(s, 2);
    s += __shfl_xor(s, 4);
    row[deg + lane] = make_int2(0, 0);   // 8 pads, one per lane
    if (lane == 0) deg_w[n] = s;
  }
  sf[t] = (n < NN && lane == 0) ? logf(s + 1.f) : 0.f;
  __syncthreads();
  for (int off = 128; off > 0; off >>= 1){
    if (t < off) sf[t] += sf[t+off];
    __syncthreads();
  }
  if (t == 0) atomicAdd(logsum, sf[0]);
}

// rel_input per layer (6x32), query-part of final MLP (64), and layer-0
// W column-sums over the h-part rows (boundary input is constant per node).
__global__ __launch_bounds__(320) void k_prep(const float* __restrict__ qw,
                                              const float* __restrict__ rel_W,
                                              const float* __restrict__ rel_b,
                                              const float* __restrict__ W1,
                                              const float* __restrict__ b1,
                                              const float* __restrict__ lin_W,
                                              float* __restrict__ rel6,
                                              float* __restrict__ qc,
                                              float* __restrict__ wcol){
  int t = threadIdx.x;
  if (t < 192){
    int l = t >> 5, j = t & 31;
    float s = rel_b[t];
    for (int d = 0; d < 32; ++d) s += qw[d] * rel_W[l*1024 + d*32 + j];
    rel6[t] = s;
  } else if (t < 256){
    int j = t - 192;
    float s = b1[j];
    for (int k = 0; k < 32; ++k) s += qw[k] * W1[(32+k)*64 + j];
    qc[j] = s;
  } else if (t < 288){
    int j = t - 256;
    float s = 0.f;
    for (int k = 0; k < 32; ++k) s += lin_W[k*32 + j];   // layer 0, h-part rows
    wcol[j] = s;
  }
}

// ROUND-5: pre-pack per-(layer,wave) weight slices in EXACT phase-2
// consumption order: k=0..31 h-part rows, then per feat kp: (P,S,I) rows,
// each as float4 of cols [w*4 .. w*4+3]. Phase 2's scalar stream becomes
// one monotone contiguous 6.6KB run per wave -> s_load merge into
// dwordx8/x16, ~4x fewer scalar ops, no stride-hopping. FP order identical.
__global__ __launch_bounds__(448) void k_wt(const float* __restrict__ lin_W,
                                            float* __restrict__ Wt){
  int lw = blockIdx.x;         // 0..47 = l*8 + w
  int l = lw >> 3, w = lw & 7;
  int k = threadIdx.x;         // 0..415 used
  if (k >= 416) return;
  int row;
  if (k < 32) row = k;
  else {
    int kk = k - 32;
    int kp = kk / 3, s = kk - kp*3;
    row = 32 + (kp >> 2)*12 + (kp & 3)*3 + s;
  }
  float4 v = *(const float4*)(lin_W + (size_t)l*13312 + row*32 + w*4);
  ((float4*)Wt)[(size_t)lw*416 + k] = v;
}

// t[n] = dot(h[n], rel_layer5) for msg_score
__global__ __launch_bounds__(256) void k_dot(const float* __restrict__ h,
                                             const float* __restrict__ rel6,
                                             float* __restrict__ tdot){
  int n0 = blockIdx.x*256 + threadIdx.x;
  int n = (n0 < NN) ? n0 : NN-1;
  const float* relr = rel6 + 5*32;
  float s = 0.f;
  #pragma unroll
  for (int d = 0; d < 32; ++d) s += h[n*32 + d] * relr[d];
  if (n0 < NN) tdot[n0] = s;
}

// ---------------- layer 0 (specialized: boundary input) ----------------
// Round-0 structure verbatim; phase-2 weights via packed Wt (layer 0).
__global__ __launch_bounds__(512, 6) void k_layer0(const float* __restrict__ rel6,
                                               const int* __restrict__ cursor,
                                               const int2* __restrict__ csr,
                                               const int* __restrict__ hidx,
                                               const float* __restrict__ Wt,
                                               const float* __restrict__ lin_b,
                                               const float* __restrict__ wcol,
                                               const float* __restrict__ deg_w,
                                               const float* __restrict__ logsum,
                                               float* __restrict__ h_next){
  __shared__ float sh[128*65];
  int tid = threadIdx.x;
  int base = blockIdx.x * 64;
  int hv0 = *hidx;

  // ---- phase 1: scalar aggregation (csr scan only) ----
  {
    int nl   = tid >> 3;
    int quad = tid & 7;
    float4 r4 = ((const float4*)(rel6))[quad];   // layer 0
    int n0 = base + nl;
    int n = (n0 < NN) ? n0 : NN-1;
    int deg = cursor[n];
    int s0 = n*BSTR, s1 = s0 + deg;
    float S1=0.f, S2=0.f, M=-INFINITY, m=INFINITY;

#define ACCS(C) { \
    float w  = __int_as_float(C.y); \
    float hv = (C.x == hv0) ? 0.f : 100.f; \
    float wm = w * hv; \
    S1 += wm; S2 += wm * hv; \
    M = fmaxf(M, wm); m = fminf(m, wm); }

    int2 cA = csr[s0],   cB = csr[s0+1], cC = csr[s0+2], cD = csr[s0+3];
    int e = s0;
    for (; e + 4 <= s1; e += 4){
      int2 nA = csr[e+4], nB = csr[e+5], nC = csr[e+6], nD = csr[e+7];
      ACCS(cA) ACCS(cB) ACCS(cC) ACCS(cD)
      cA = nA; cB = nB; cC = nC; cD = nD;
    }
    if (e < s1){
      ACCS(cA)
      if (e + 1 < s1){
        ACCS(cB)
        if (e + 2 < s1) ACCS(cC)
      }
    }
#undef ACCS

    float bnd = (n == hv0) ? 0.f : 100.f;
    float cntf = (float)(deg + 1);
#define FIN(cc, rc) { \
    float mxv, mnv; \
    if (deg > 0){ \
      float em = (rc >= 0.f) ? rc*M : rc*m; \
      float en = (rc >= 0.f) ? rc*m : rc*M; \
      mxv = fmaxf(em, bnd); mnv = fminf(en, bnd); \
    } else { mxv = bnd; mnv = bnd; } \
    float meanv = (rc*S1 + bnd) / cntf; \
    float sq    = (rc*rc*S2 + bnd*bnd) / cntf; \
    float sdv   = sqrtf(fmaxf(sq - meanv*meanv, 1e-6f)); \
    int d = quad*4 + cc; \
    sh[(d*4+0)*65 + nl] = meanv; \
    sh[(d*4+1)*65 + nl] = mxv; \
    sh[(d*4+2)*65 + nl] = mnv; \
    sh[(d*4+3)*65 + nl] = sdv; }
    FIN(0, r4.x) FIN(1, r4.y) FIN(2, r4.z) FIN(3, r4.w)
#undef FIN
  }
  __syncthreads();

  // ---- phase 2: linear; x-part = bnd * wcol; 3-sum hoist of sc/iv ----
  {
    int lane = tid & 63;
    int grp = __builtin_amdgcn_readfirstlane(tid >> 6);
    int j0 = grp * 4;
    const float* Ww = Wt + (size_t)grp*1664 + 128;   // layer 0 slice, feat part
    int n0 = base + lane;
    int n = (n0 < NN) ? n0 : NN-1;
    float mean = *logsum / (float)NN;
    float sc = logf(deg_w[n] + 1.f) / mean;
    float iv = 1.f / fmaxf(sc, 0.01f);
    float bndn = (n == hv0) ? 0.f : 100.f;
    v2f a01p={0,0}, a23p={0,0}, a01s={0,0}, a23s={0,0}, a01i={0,0}, a23i={0,0};

    for (int kp = 0; kp < 128; ++kp){
      float f = sh[kp*65 + lane];
      const v2f* wp = (const v2f*)(Ww + kp*12);
      v2f fv; fv[0]=f; fv[1]=f;
      a01p += fv*wp[0];  a23p += fv*wp[1];
      a01s += fv*wp[2];  a23s += fv*wp[3];
      a01i += fv*wp[4];  a23i += fv*wp[5];
    }
    v2f sc2; sc2[0]=sc; sc2[1]=sc;
    v2f iv2; iv2[0]=iv; iv2[1]=iv;
    v2f a01 = a01p + sc2*a01s + iv2*a01i;
    v2f a23 = a23p + sc2*a23s + iv2*a23i;
    a01[0] += lin_b[j0+0] + bndn*wcol[j0+0];
    a01[1] += lin_b[j0+1] + bndn*wcol[j0+1];
    a23[0] += lin_b[j0+2] + bndn*wcol[j0+2];
    a23[1] += lin_b[j0+3] + bndn*wcol[j0+3];

    if (n0 < NN){
      float vs[4] = { a01[0], a01[1], a23[0], a23[1] };
      #pragma unroll
      for (int j = 0; j < 4; ++j)
        h_next[n0*32 + j0 + j] = fmaxf(vs[j], 0.f);
    }
  }
}

// ---------------- fused per-layer kernel (layers 1..5) ----------------
// Round-0 structure verbatim (the 60us anchor); the ONLY change is phase-2
// weight addressing via the packed Wt stream (values + accumulation order
// bit-identical: wp[0..5] == old w2[0],w2[1],w2[16],w2[17],w2[32],w2[33]).
// Rejected levers (counter-proven): SW-pipelined gathers (r1 spill
// WRITE 0.4->17.6MB; r2 compiler re-sink, occupancy loss); smaller blocks
// (r3: occupancy pinned ~41%, non-uniform j0 loses s_loads -> 2x); phase-2
// LDS transpose (r4: 60->83us, b128 row reads worse than lane-contiguous
// b32 stream). PRED (l=5): predecessor in phase 1, final MLP in epilogue.
template<bool PRED>
__global__ __launch_bounds__(512, 6) void k_layer(const float* __restrict__ h,
                                               const float* __restrict__ rel6,
                                               const int* __restrict__ cursor,
                                               const int2* __restrict__ csr,
                                               const int* __restrict__ hidx,
                                               const float* __restrict__ tdot,
                                               const float* __restrict__ Wt,
                                               const float* __restrict__ lin_b,
                                               const float* __restrict__ deg_w,
                                               const float* __restrict__ logsum,
                                               float* __restrict__ h_next,
                                               float* __restrict__ pred_out,
                                               const float* __restrict__ qc,
                                               const float* __restrict__ W1,
                                               const float* __restrict__ W2,
                                               const float* __restrict__ b2,
                                               float* __restrict__ out_score,
                                               int l){
  __shared__ float sh[128*65];
  int tid = threadIdx.x;
  int base = blockIdx.x * 64;
  int hv0 = *hidx;

  // ---- phase 1: aggregation (one 8-lane group per node, unroll-4) ----
  {
    int nl   = tid >> 3;
    int quad = tid & 7;
    float4 r4 = ((const float4*)(rel6 + l*32))[quad];
    int n0 = base + nl;
    bool valid = n0 < NN;
    int n = valid ? n0 : NN-1;
    int deg = cursor[n];
    int s0 = n*BSTR, s1 = s0 + deg;
    v2f S1xy={0,0}, S1zw={0,0}, S2xy={0,0}, S2zw={0,0};
    float M0=-INFINITY,M1=-INFINITY,M2=-INFINITY,M3=-INFINITY;
    float m0=INFINITY,m1=INFINITY,m2=INFINITY,m3=INFINITY;
    float best=-INFINITY; int bi=NN;

#define ACC1(C, A, T) { \
    float w = __int_as_float(C.y); \
    v2f wv; wv[0]=w; wv[1]=w; \
    v2f axy; axy[0]=A.x; axy[1]=A.y; \
    v2f azw; azw[0]=A.z; azw[1]=A.w; \
    v2f pxy = wv*axy, pzw = wv*azw; \
    S1xy += pxy; S1zw += pzw; \
    S2xy += pxy*axy; S2zw += pzw*azw; \
    M0=fmaxf(M0,pxy[0]); M1=fmaxf(M1,pxy[1]); M2=fmaxf(M2,pzw[0]); M3=fmaxf(M3,pzw[1]); \
    m0=fminf(m0,pxy[0]); m1=fminf(m1,pxy[1]); m2=fminf(m2,pzw[0]); m3=fminf(m3,pzw[1]); \
    if (PRED){ \
      float sv = w*T; \
      if (sv > best){ best = sv; bi = C.x; } \
      else if (sv == best && C.x < bi) bi = C.x; \
    } }

    int2 cA = csr[s0],   cB = csr[s0+1], cC = csr[s0+2], cD = csr[s0+3];
    int e = s0;
    for (; e + 4 <= s1; e += 4){
      float4 a  = ((const float4*)(h + cA.x*32))[quad];
      float4 b  = ((const float4*)(h + cB.x*32))[quad];
      float4 c4 = ((const float4*)(h + cC.x*32))[quad];
      float4 d4 = ((const float4*)(h + cD.x*32))[quad];
      float tA=0.f, tB=0.f, tC=0.f, tD=0.f;
      if (PRED){ tA = tdot[cA.x]; tB = tdot[cB.x]; tC = tdot[cC.x]; tD = tdot[cD.x]; }
      int2 nA = csr[e+4], nB = csr[e+5], nC = csr[e+6], nD = csr[e+7];
      ACC1(cA, a, tA)
      ACC1(cB, b, tB)
      ACC1(cC, c4, tC)
      ACC1(cD, d4, tD)
      cA = nA; cB = nB; cC = nC; cD = nD;
    }
    if (e < s1){
      float4 a = ((const float4*)(h + cA.x*32))[quad];
      float tA = 0.f; if (PRED) tA = tdot[cA.x];
      ACC1(cA, a, tA)
      if (e + 1 < s1){
        float4 b = ((const float4*)(h + cB.x*32))[quad];
        float tB = 0.f; if (PRED) tB = tdot[cB.x];
        ACC1(cB, b, tB)
        if (e + 2 < s1){
          float4 c4 = ((const float4*)(h + cC.x*32))[quad];
          float tC = 0.f; if (PRED) tC = tdot[cC.x];
          ACC1(cC, c4, tC)
        }
      }
    }
#undef ACC1

    float bnd = (n == hv0) ? 0.f : 100.f;
    float cntf = (float)(deg + 1);
#define FIN(cc, rc, S1c, S2c, Mc, mc) { \
    float mxv, mnv; \
    if (deg > 0){ \
      float em = (rc >= 0.f) ? rc*Mc : rc*mc; \
      float en = (rc >= 0.f) ? rc*mc : rc*Mc; \
      mxv = fmaxf(em, bnd); mnv = fminf(en, bnd); \
    } else { mxv = bnd; mnv = bnd; } \
    float meanv = (rc*S1c + bnd) / cntf; \
    float sq    = (rc*rc*S2c + bnd*bnd) / cntf; \
    float sdv   = sqrtf(fmaxf(sq - meanv*meanv, 1e-6f)); \
    int d = quad*4 + cc; \
    sh[(d*4+0)*65 + nl] = meanv; \
    sh[(d*4+1)*65 + nl] = mxv; \
    sh[(d*4+2)*65 + nl] = mnv; \
    sh[(d*4+3)*65 + nl] = sdv; }
    FIN(0, r4.x, S1xy[0], S2xy[0], M0, m0)
    FIN(1, r4.y, S1xy[1], S2xy[1], M1, m1)
    FIN(2, r4.z, S1zw[0], S2zw[0], M2, m2)
    FIN(3, r4.w, S1zw[1], S2zw[1], M3, m3)
#undef FIN
    if (PRED && valid && quad == 0){
      float ss = (n == hv0) ? 0.f : 3200.f;   // boundary self-loop row sum, w=1
      if (ss > best){ best = ss; bi = n; }
      else if (ss == best && n < bi) bi = n;
      pred_out[n] = (float)bi;
    }
  }
  __syncthreads();

  // ---- phase 2: linear (8 waves, wave w -> j0 = w*4; node = lane) ----
  // 3-sum hoist: acc = P + sc*S + iv*I applied once at the end.
  {
    int lane = tid & 63;
    int grp = __builtin_amdgcn_readfirstlane(tid >> 6);
    int j0 = grp * 4;
    const float* Ww = Wt + (size_t)(l*8 + grp)*1664;   // packed slice (floats)
    int n0 = base + lane;
    int n = (n0 < NN) ? n0 : NN-1;
    float mean = *logsum / (float)NN;
    float sc = logf(deg_w[n] + 1.f) / mean;
    float iv = 1.f / fmaxf(sc, 0.01f);
    const float4* hr = (const float4*)(h + (size_t)n*32);
    float4 x0=hr[0],x1=hr[1],x2=hr[2],x3=hr[3],x4=hr[4],x5=hr[5],x6=hr[6],x7=hr[7];
    v2f a01p={0,0}, a23p={0,0}, a01s={0,0}, a23s={0,0}, a01i={0,0}, a23i={0,0};

#define KONE(XV, K) { \
    v2f xv2; xv2[0] = XV; xv2[1] = XV; \
    const v2f* wr2 = (const v2f*)(Ww + (K)*4); \
    a01p += xv2 * wr2[0]; \
    a23p += xv2 * wr2[1]; }
#define KQ(X, KB) KONE(X.x, KB+0) KONE(X.y, KB+1) KONE(X.z, KB+2) KONE(X.w, KB+3)
    KQ(x0, 0) KQ(x1, 4) KQ(x2, 8) KQ(x3, 12)
    KQ(x4, 16) KQ(x5, 20) KQ(x6, 24) KQ(x7, 28)
#undef KQ
#undef KONE

    const float* Wf = Ww + 128;   // feat part: 3 float4 per kp, contiguous
    for (int kp = 0; kp < 128; ++kp){
      float f = sh[kp*65 + lane];
      const v2f* wp = (const v2f*)(Wf + kp*12);
      v2f fv; fv[0]=f; fv[1]=f;
      a01p += fv*wp[0];  a23p += fv*wp[1];
      a01s += fv*wp[2];  a23s += fv*wp[3];
      a01i += fv*wp[4];  a23i += fv*wp[5];
    }
    v2f sc2; sc2[0]=sc; sc2[1]=sc;
    v2f iv2; iv2[0]=iv; iv2[1]=iv;
    v2f a01 = a01p + sc2*a01s + iv2*a01i;
    v2f a23 = a23p + sc2*a23s + iv2*a23i;
    a01[0] += lin_b[l*32 + j0 + 0];
    a01[1] += lin_b[l*32 + j0 + 1];
    a23[0] += lin_b[l*32 + j0 + 2];
    a23[1] += lin_b[l*32 + j0 + 3];

    float v0r = fmaxf(a01[0], 0.f), v1r = fmaxf(a01[1], 0.f);
    float v2r = fmaxf(a23[0], 0.f), v3r = fmaxf(a23[1], 0.f);

    if (!PRED){
      if (n0 < NN){
        h_next[n0*32 + j0 + 0] = v0r;
        h_next[n0*32 + j0 + 1] = v1r;
        h_next[n0*32 + j0 + 2] = v2r;
        h_next[n0*32 + j0 + 3] = v3r;
      }
    } else {
      // ---- fused final MLP (l=5): h6 never leaves the block ----
      __syncthreads();                    // all phase-2 sh reads complete
      sh[(j0+0)*65 + lane] = v0r;         // stage h6 rows 0..31 (65-stride)
      sh[(j0+1)*65 + lane] = v1r;
      sh[(j0+2)*65 + lane] = v2r;
      sh[(j0+3)*65 + lane] = v3r;
      __syncthreads();
      int node = tid & 63;
      int grp2 = __builtin_amdgcn_readfirstlane(tid >> 6);   // 0..7
      int jm = grp2*8;                    // wave-uniform -> W1 s_loads
      v2f b0, b1v, b2v, b3;
      b0[0]=qc[jm+0]; b0[1]=qc[jm+1]; b1v[0]=qc[jm+2]; b1v[1]=qc[jm+3];
      b2v[0]=qc[jm+4]; b2v[1]=qc[jm+5]; b3[0]=qc[jm+6]; b3[1]=qc[jm+7];
      for (int k = 0; k < 32; ++k){
        float xv = sh[k*65 + node];
        const v2f* wr = (const v2f*)(W1 + k*64 + jm);
        v2f xv2; xv2[0]=xv; xv2[1]=xv;
        b0 += xv2*wr[0]; b1v += xv2*wr[1]; b2v += xv2*wr[2]; b3 += xv2*wr[3];
      }
      float part = fmaxf(b0[0],0.f)*W2[jm+0] + fmaxf(b0[1],0.f)*W2[jm+1]
                 + fmaxf(b1v[0],0.f)*W2[jm+2] + fmaxf(b1v[1],0.f)*W2[jm+3]
                 + fmaxf(b2v[0],0.f)*W2[jm+4] + fmaxf(b2v[1],0.f)*W2[jm+5]
                 + fmaxf(b3[0],0.f)*W2[jm+6] + fmaxf(b3[1],0.f)*W2[jm+7];
      sh[2080 + node*9 + grp2] = part;    // past the 32 staged rows (2080)
      __syncthreads();
      if (tid < 64){
        float s = b2[0];
        #pragma unroll
        for (int g = 0; g < 8; ++g) s += sh[2080 + tid*9 + g];
        if (base + tid < NN) out_score[base + tid] = s;
      }
    }
  }
}

// ---------------- host launch ----------------
extern "C" void kernel_launch(void* const* d_in, const int* in_sizes, int n_in,
                              void* d_out, int out_size, void* d_ws, size_t ws_size,
                              hipStream_t stream){
  const int*   node_in  = (const int*)d_in[0];
  const int*   node_out = (const int*)d_in[1];
  const float* ew       = (const float*)d_in[2];
  const int*   hidx     = (const int*)d_in[3];
  const float* qw       = (const float*)d_in[4];
  const float* rel_W    = (const float*)d_in[5];
  const float* rel_b    = (const float*)d_in[6];
  const float* lin_W    = (const float*)d_in[7];
  const float* lin_b    = (const float*)d_in[8];
  const float* W1       = (const float*)d_in[9];
  const float* b1       = (const float*)d_in[10];
  const float* W2       = (const float*)d_in[11];
  const float* b2       = (const float*)d_in[12];
  float* out_score = (float*)d_out;
  float* out_pred  = out_score + NN;

  char* w = (char*)d_ws;
  size_t off = 0;
  auto take = [&](size_t bytes)->char*{
    char* p = w + off;
    off = (off + bytes + 255) & ~(size_t)255;
    return p;
  };
  size_t bucket_elems = (size_t)NN * BSTR;            // int2 entries
  int2*  csr      = (int2*)take(bucket_elems*8);
  // contiguous zero block: cursor | deg_w | logsum
  char*  zb       = take((size_t)NN*4 + (size_t)NN*4 + 256);
  int*   cursor   = (int*)zb;
  float* deg_w    = (float*)(cursor + NN);
  float* logsum   = (float*)(deg_w + NN);
  int zc = NN + NN + 64;

  float* rel6      = (float*)take(192*4);
  float* qc        = (float*)take(64*4);
  float* wcol      = (float*)take(32*4);
  float* Wt        = (float*)take((size_t)48*416*16);   // packed weights
  float* tdot      = (float*)take((size_t)NN*4);
  float* h_a       = (float*)take((size_t)NN*32*4);
  float* h_b       = (float*)take((size_t)NN*32*4);

  int nb  = (NN + 255) / 256;   // 196
  int nsb = (NN + 31) / 32;     // 1563 (k_sumw: 32 nodes/block)
  int nlb = (NN + 63) / 64;     // 782
  k_zero   <<<(zc+255)/256, 256, 0, stream>>>((float*)zb, zc);
  k_fillcsr<<<NPART*CPB, 256, 0, stream>>>(node_in, node_out, ew, cursor, csr);
  k_sumw   <<<nsb, 256, 0, stream>>>(csr, cursor, deg_w, logsum);
  k_prep   <<<1, 320, 0, stream>>>(qw, rel_W, rel_b, W1, b1, lin_W, rel6, qc, wcol);
  k_wt     <<<48, 448, 0, stream>>>(lin_W, Wt);

  // layer 0 (specialized, no h input)
  k_layer0<<<nlb, 512, 0, stream>>>(rel6, cursor, csr, hidx, Wt, lin_b,
                                    wcol, deg_w, logsum, h_a);

  float* hc = h_a;
  float* hn = h_b;
  for (int l = 1; l < 6; ++l){
    if (l == 5){
      k_dot<<<nb, 256, 0, stream>>>(hc, rel6, tdot);
      k_layer<true><<<nlb, 512, 0, stream>>>(hc, rel6, cursor, csr, hidx, tdot,
                                             Wt, lin_b, deg_w, logsum,
                                             hn, out_pred,
                                             qc, W1, W2, b2, out_score, l);
    } else {
      k_layer<false><<<nlb, 512, 0, stream>>>(hc, rel6, cursor, csr, hidx, tdot,
                                              Wt, lin_b, deg_w, logsum,
                                              hn, out_pred,
                                              qc, W1, W2, b2, out_score, l);
    }
    float* t1 = hc; hc = hn; hn = t1;
  }
}

// Round 6
// 378.032 us; speedup vs baseline: 1.8170x; 1.0035x over previous
//
#include <hip/hip_runtime.h>
#include <math.h>

#define NN 50000
#define EE 800000
#define DD 32
#define BSTR 64    // bucket stride (max degree ~45 at Poisson(16); +8 pad fits)
#define NPART 8    // node-range partitions, mapped to XCDs via blockIdx&7
#define CPB 128    // edge chunks per partition (grid = 8*128 = 1024 blocks)

typedef float v2f __attribute__((ext_vector_type(2)));

__device__ inline v2f vmax2(v2f a, v2f b){ v2f r; r[0]=fmaxf(a[0],b[0]); r[1]=fmaxf(a[1],b[1]); return r; }
__device__ inline v2f vmin2(v2f a, v2f b){ v2f r; r[0]=fminf(a[0],b[0]); r[1]=fminf(a[1],b[1]); return r; }

// ---------------- setup kernels ----------------

__global__ __launch_bounds__(256) void k_zero(float* p, int count){
  int i = blockIdx.x*256 + threadIdx.x;
  if (i < count) p[i] = 0.f;
}

// XCD-partitioned one-pass CSR build (R16-proven: cut write-amp 51->~12 MB).
__global__ __launch_bounds__(256) void k_fillcsr(const int* __restrict__ node_in,
                                                 const int* __restrict__ node_out,
                                                 const float* __restrict__ ew,
                                                 int* __restrict__ cursor,
                                                 int2* __restrict__ csr){
  int part  = blockIdx.x & (NPART-1);
  int group = blockIdx.x >> 3;
  const int per = (EE + CPB - 1) / CPB;   // 6250
  int e0 = group * per;
  int e1 = (e0 + per < EE) ? (e0 + per) : EE;
  unsigned lo = (unsigned)part * 6250u;
  unsigned hi = lo + 6250u;
  for (int e = e0 + threadIdx.x; e < e1; e += 256){
    unsigned o = (unsigned)node_out[e];
    if (o >= lo && o < hi){
      int pos = atomicAdd(&cursor[o], 1);
      int2 v; v.x = node_in[e]; v.y = __float_as_int(ew[e]);
      csr[o*BSTR + pos] = v;
    }
  }
}

// per-node sum(w): 8-lane group per node, coalesced bucket reads, shfl_xor
// reduce; zero the 8-entry pad tail in parallel; block logsum reduce.
__global__ __launch_bounds__(256) void k_sumw(int2* __restrict__ csr,
                                              const int* __restrict__ cursor,
                                              float* __restrict__ deg_w,
                                              float* __restrict__ logsum){
  __shared__ float sf[256];
  int t = threadIdx.x;
  int g = t >> 3, lane = t & 7;
  int n = blockIdx.x*32 + g;
  float s = 0.f;
  if (n < NN){
    int deg = cursor[n];
    int2* row = csr + n*BSTR;
    for (int i = lane; i < deg; i += 8) s += __int_as_float(row[i].y);
    s += __shfl_xor(s, 1);
    s += __shfl_xor(s, 2);
    s += __shfl_xor(s, 4);
    row[deg + lane] = make_int2(0, 0);   // 8 pads, one per lane
    if (lane == 0) deg_w[n] = s;
  }
  sf[t] = (n < NN && lane == 0) ? logf(s + 1.f) : 0.f;
  __syncthreads();
  for (int off = 128; off > 0; off >>= 1){
    if (t < off) sf[t] += sf[t+off];
    __syncthreads();
  }
  if (t == 0) atomicAdd(logsum, sf[0]);
}

// ROUND-6: k_prep + k_wt merged into one dispatch (one fewer serialized
// launch). Blocks 0..47: pack per-(layer,wave) weight slices in EXACT
// phase-2 consumption order (R5-proven: contiguous monotone s_load stream,
// k_layer 60->50us). Block 48: rel_input per layer, query-part of final
// MLP, layer-0 W column-sums.
__global__ __launch_bounds__(448) void k_prep2(const float* __restrict__ qw,
                                               const float* __restrict__ rel_W,
                                               const float* __restrict__ rel_b,
                                               const float* __restrict__ W1,
                                               const float* __restrict__ b1,
                                               const float* __restrict__ lin_W,
                                               float* __restrict__ rel6,
                                               float* __restrict__ qc,
                                               float* __restrict__ wcol,
                                               float* __restrict__ Wt){
  if (blockIdx.x < 48){
    int lw = blockIdx.x;         // 0..47 = l*8 + w
    int l = lw >> 3, w = lw & 7;
    int k = threadIdx.x;         // 0..415 used
    if (k >= 416) return;
    int row;
    if (k < 32) row = k;
    else {
      int kk = k - 32;
      int kp = kk / 3, s = kk - kp*3;
      row = 32 + (kp >> 2)*12 + (kp & 3)*3 + s;
    }
    float4 v = *(const float4*)(lin_W + (size_t)l*13312 + row*32 + w*4);
    ((float4*)Wt)[(size_t)lw*416 + k] = v;
  } else {
    int t = threadIdx.x;
    if (t < 192){
      int l = t >> 5, j = t & 31;
      float s = rel_b[t];
      for (int d = 0; d < 32; ++d) s += qw[d] * rel_W[l*1024 + d*32 + j];
      rel6[t] = s;
    } else if (t < 256){
      int j = t - 192;
      float s = b1[j];
      for (int k = 0; k < 32; ++k) s += qw[k] * W1[(32+k)*64 + j];
      qc[j] = s;
    } else if (t < 288){
      int j = t - 256;
      float s = 0.f;
      for (int k = 0; k < 32; ++k) s += lin_W[k*32 + j];   // layer 0, h-part rows
      wcol[j] = s;
    }
  }
}

// ---------------- layer 0 (specialized: boundary input) ----------------
// Round-0 structure verbatim; phase-2 weights via packed Wt (layer 0).
__global__ __launch_bounds__(512, 6) void k_layer0(const float* __restrict__ rel6,
                                               const int* __restrict__ cursor,
                                               const int2* __restrict__ csr,
                                               const int* __restrict__ hidx,
                                               const float* __restrict__ Wt,
                                               const float* __restrict__ lin_b,
                                               const float* __restrict__ wcol,
                                               const float* __restrict__ deg_w,
                                               const float* __restrict__ logsum,
                                               float* __restrict__ h_next){
  __shared__ float sh[128*65];
  int tid = threadIdx.x;
  int base = blockIdx.x * 64;
  int hv0 = *hidx;

  // ---- phase 1: scalar aggregation (csr scan only) ----
  {
    int nl   = tid >> 3;
    int quad = tid & 7;
    float4 r4 = ((const float4*)(rel6))[quad];   // layer 0
    int n0 = base + nl;
    int n = (n0 < NN) ? n0 : NN-1;
    int deg = cursor[n];
    int s0 = n*BSTR, s1 = s0 + deg;
    float S1=0.f, S2=0.f, M=-INFINITY, m=INFINITY;

#define ACCS(C) { \
    float w  = __int_as_float(C.y); \
    float hv = (C.x == hv0) ? 0.f : 100.f; \
    float wm = w * hv; \
    S1 += wm; S2 += wm * hv; \
    M = fmaxf(M, wm); m = fminf(m, wm); }

    int2 cA = csr[s0],   cB = csr[s0+1], cC = csr[s0+2], cD = csr[s0+3];
    int e = s0;
    for (; e + 4 <= s1; e += 4){
      int2 nA = csr[e+4], nB = csr[e+5], nC = csr[e+6], nD = csr[e+7];
      ACCS(cA) ACCS(cB) ACCS(cC) ACCS(cD)
      cA = nA; cB = nB; cC = nC; cD = nD;
    }
    if (e < s1){
      ACCS(cA)
      if (e + 1 < s1){
        ACCS(cB)
        if (e + 2 < s1) ACCS(cC)
      }
    }
#undef ACCS

    float bnd = (n == hv0) ? 0.f : 100.f;
    float cntf = (float)(deg + 1);
#define FIN(cc, rc) { \
    float mxv, mnv; \
    if (deg > 0){ \
      float em = (rc >= 0.f) ? rc*M : rc*m; \
      float en = (rc >= 0.f) ? rc*m : rc*M; \
      mxv = fmaxf(em, bnd); mnv = fminf(en, bnd); \
    } else { mxv = bnd; mnv = bnd; } \
    float meanv = (rc*S1 + bnd) / cntf; \
    float sq    = (rc*rc*S2 + bnd*bnd) / cntf; \
    float sdv   = sqrtf(fmaxf(sq - meanv*meanv, 1e-6f)); \
    int d = quad*4 + cc; \
    sh[(d*4+0)*65 + nl] = meanv; \
    sh[(d*4+1)*65 + nl] = mxv; \
    sh[(d*4+2)*65 + nl] = mnv; \
    sh[(d*4+3)*65 + nl] = sdv; }
    FIN(0, r4.x) FIN(1, r4.y) FIN(2, r4.z) FIN(3, r4.w)
#undef FIN
  }
  __syncthreads();

  // ---- phase 2: linear; x-part = bnd * wcol; 3-sum hoist of sc/iv ----
  {
    int lane = tid & 63;
    int grp = __builtin_amdgcn_readfirstlane(tid >> 6);
    int j0 = grp * 4;
    const float* Ww = Wt + (size_t)grp*1664 + 128;   // layer 0 slice, feat part
    int n0 = base + lane;
    int n = (n0 < NN) ? n0 : NN-1;
    float mean = *logsum / (float)NN;
    float sc = logf(deg_w[n] + 1.f) / mean;
    float iv = 1.f / fmaxf(sc, 0.01f);
    float bndn = (n == hv0) ? 0.f : 100.f;
    v2f a01p={0,0}, a23p={0,0}, a01s={0,0}, a23s={0,0}, a01i={0,0}, a23i={0,0};

    for (int kp = 0; kp < 128; ++kp){
      float f = sh[kp*65 + lane];
      const v2f* wp = (const v2f*)(Ww + kp*12);
      v2f fv; fv[0]=f; fv[1]=f;
      a01p += fv*wp[0];  a23p += fv*wp[1];
      a01s += fv*wp[2];  a23s += fv*wp[3];
      a01i += fv*wp[4];  a23i += fv*wp[5];
    }
    v2f sc2; sc2[0]=sc; sc2[1]=sc;
    v2f iv2; iv2[0]=iv; iv2[1]=iv;
    v2f a01 = a01p + sc2*a01s + iv2*a01i;
    v2f a23 = a23p + sc2*a23s + iv2*a23i;
    a01[0] += lin_b[j0+0] + bndn*wcol[j0+0];
    a01[1] += lin_b[j0+1] + bndn*wcol[j0+1];
    a23[0] += lin_b[j0+2] + bndn*wcol[j0+2];
    a23[1] += lin_b[j0+3] + bndn*wcol[j0+3];

    if (n0 < NN){
      float vs[4] = { a01[0], a01[1], a23[0], a23[1] };
      #pragma unroll
      for (int j = 0; j < 4; ++j)
        h_next[n0*32 + j0 + j] = fmaxf(vs[j], 0.f);
    }
  }
}

// ---------------- fused per-layer kernel (layers 1..5) ----------------
// Round-5 structure (the 50us anchor: packed-Wt phase 2). ROUND-6 deltas:
// (a) phase-1 max/min tracked as v2f elementwise -> compiler may emit
//     v_pk_max/min_f32 (exact ops, zero numerical risk; neutral if not);
// (b) MODE=1 (l=4): tdot fused into the epilogue -- stage h5 rows in LDS,
//     64 threads compute the 32-term dot in k_dot's exact ascending order
//     (bit-identical tdot), saving the k_dot dispatch + 6.4MB h re-read;
// (c) MODE=2 (l=5): PRED predecessor tracking + fused final MLP (as r5).
// Rejected levers (counter-proven): SW-pipelined gathers (r1 spill, r2
// compiler re-sink); smaller blocks (r3: non-uniform j0 loses s_loads);
// phase-2 LDS transpose (r4: b128 row reads worse than b32 stream).
template<int MODE>
__global__ __launch_bounds__(512, 6) void k_layer(const float* __restrict__ h,
                                               const float* __restrict__ rel6,
                                               const int* __restrict__ cursor,
                                               const int2* __restrict__ csr,
                                               const int* __restrict__ hidx,
                                               const float* __restrict__ tdot,
                                               const float* __restrict__ Wt,
                                               const float* __restrict__ lin_b,
                                               const float* __restrict__ deg_w,
                                               const float* __restrict__ logsum,
                                               float* __restrict__ h_next,
                                               float* __restrict__ pred_out,
                                               const float* __restrict__ qc,
                                               const float* __restrict__ W1,
                                               const float* __restrict__ W2,
                                               const float* __restrict__ b2,
                                               float* __restrict__ out_score,
                                               float* __restrict__ tdot_out,
                                               int l){
  __shared__ float sh[128*65];
  int tid = threadIdx.x;
  int base = blockIdx.x * 64;
  int hv0 = *hidx;

  // ---- phase 1: aggregation (one 8-lane group per node, unroll-4) ----
  {
    int nl   = tid >> 3;
    int quad = tid & 7;
    float4 r4 = ((const float4*)(rel6 + l*32))[quad];
    int n0 = base + nl;
    bool valid = n0 < NN;
    int n = valid ? n0 : NN-1;
    int deg = cursor[n];
    int s0 = n*BSTR, s1 = s0 + deg;
    v2f S1xy={0,0}, S1zw={0,0}, S2xy={0,0}, S2zw={0,0};
    v2f Mxy={-INFINITY,-INFINITY}, Mzw={-INFINITY,-INFINITY};
    v2f mxy={ INFINITY, INFINITY}, mzw={ INFINITY, INFINITY};
    float best=-INFINITY; int bi=NN;

#define ACC1(C, A, T) { \
    float w = __int_as_float(C.y); \
    v2f wv; wv[0]=w; wv[1]=w; \
    v2f axy; axy[0]=A.x; axy[1]=A.y; \
    v2f azw; azw[0]=A.z; azw[1]=A.w; \
    v2f pxy = wv*axy, pzw = wv*azw; \
    S1xy += pxy; S1zw += pzw; \
    S2xy += pxy*axy; S2zw += pzw*azw; \
    Mxy = vmax2(Mxy, pxy); Mzw = vmax2(Mzw, pzw); \
    mxy = vmin2(mxy, pxy); mzw = vmin2(mzw, pzw); \
    if (MODE==2){ \
      float sv = w*T; \
      if (sv > best){ best = sv; bi = C.x; } \
      else if (sv == best && C.x < bi) bi = C.x; \
    } }

    int2 cA = csr[s0],   cB = csr[s0+1], cC = csr[s0+2], cD = csr[s0+3];
    int e = s0;
    for (; e + 4 <= s1; e += 4){
      float4 a  = ((const float4*)(h + cA.x*32))[quad];
      float4 b  = ((const float4*)(h + cB.x*32))[quad];
      float4 c4 = ((const float4*)(h + cC.x*32))[quad];
      float4 d4 = ((const float4*)(h + cD.x*32))[quad];
      float tA=0.f, tB=0.f, tC=0.f, tD=0.f;
      if (MODE==2){ tA = tdot[cA.x]; tB = tdot[cB.x]; tC = tdot[cC.x]; tD = tdot[cD.x]; }
      int2 nA = csr[e+4], nB = csr[e+5], nC = csr[e+6], nD = csr[e+7];
      ACC1(cA, a, tA)
      ACC1(cB, b, tB)
      ACC1(cC, c4, tC)
      ACC1(cD, d4, tD)
      cA = nA; cB = nB; cC = nC; cD = nD;
    }
    if (e < s1){
      float4 a = ((const float4*)(h + cA.x*32))[quad];
      float tA = 0.f; if (MODE==2) tA = tdot[cA.x];
      ACC1(cA, a, tA)
      if (e + 1 < s1){
        float4 b = ((const float4*)(h + cB.x*32))[quad];
        float tB = 0.f; if (MODE==2) tB = tdot[cB.x];
        ACC1(cB, b, tB)
        if (e + 2 < s1){
          float4 c4 = ((const float4*)(h + cC.x*32))[quad];
          float tC = 0.f; if (MODE==2) tC = tdot[cC.x];
          ACC1(cC, c4, tC)
        }
      }
    }
#undef ACC1

    float bnd = (n == hv0) ? 0.f : 100.f;
    float cntf = (float)(deg + 1);
#define FIN(cc, rc, S1c, S2c, Mc, mc) { \
    float mxv, mnv; \
    if (deg > 0){ \
      float em = (rc >= 0.f) ? rc*Mc : rc*mc; \
      float en = (rc >= 0.f) ? rc*mc : rc*Mc; \
      mxv = fmaxf(em, bnd); mnv = fminf(en, bnd); \
    } else { mxv = bnd; mnv = bnd; } \
    float meanv = (rc*S1c + bnd) / cntf; \
    float sq    = (rc*rc*S2c + bnd*bnd) / cntf; \
    float sdv   = sqrtf(fmaxf(sq - meanv*meanv, 1e-6f)); \
    int d = quad*4 + cc; \
    sh[(d*4+0)*65 + nl] = meanv; \
    sh[(d*4+1)*65 + nl] = mxv; \
    sh[(d*4+2)*65 + nl] = mnv; \
    sh[(d*4+3)*65 + nl] = sdv; }
    FIN(0, r4.x, S1xy[0], S2xy[0], Mxy[0], mxy[0])
    FIN(1, r4.y, S1xy[1], S2xy[1], Mxy[1], mxy[1])
    FIN(2, r4.z, S1zw[0], S2zw[0], Mzw[0], mzw[0])
    FIN(3, r4.w, S1zw[1], S2zw[1], Mzw[1], mzw[1])
#undef FIN
    if (MODE==2 && valid && quad == 0){
      float ss = (n == hv0) ? 0.f : 3200.f;   // boundary self-loop row sum, w=1
      if (ss > best){ best = ss; bi = n; }
      else if (ss == best && n < bi) bi = n;
      pred_out[n] = (float)bi;
    }
  }
  __syncthreads();

  // ---- phase 2: linear (8 waves, wave w -> j0 = w*4; node = lane) ----
  // 3-sum hoist: acc = P + sc*S + iv*I applied once at the end.
  {
    int lane = tid & 63;
    int grp = __builtin_amdgcn_readfirstlane(tid >> 6);
    int j0 = grp * 4;
    const float* Ww = Wt + (size_t)(l*8 + grp)*1664;   // packed slice (floats)
    int n0 = base + lane;
    int n = (n0 < NN) ? n0 : NN-1;
    float mean = *logsum / (float)NN;
    float sc = logf(deg_w[n] + 1.f) / mean;
    float iv = 1.f / fmaxf(sc, 0.01f);
    const float4* hr = (const float4*)(h + (size_t)n*32);
    float4 x0=hr[0],x1=hr[1],x2=hr[2],x3=hr[3],x4=hr[4],x5=hr[5],x6=hr[6],x7=hr[7];
    v2f a01p={0,0}, a23p={0,0}, a01s={0,0}, a23s={0,0}, a01i={0,0}, a23i={0,0};

#define KONE(XV, K) { \
    v2f xv2; xv2[0] = XV; xv2[1] = XV; \
    const v2f* wr2 = (const v2f*)(Ww + (K)*4); \
    a01p += xv2 * wr2[0]; \
    a23p += xv2 * wr2[1]; }
#define KQ(X, KB) KONE(X.x, KB+0) KONE(X.y, KB+1) KONE(X.z, KB+2) KONE(X.w, KB+3)
    KQ(x0, 0) KQ(x1, 4) KQ(x2, 8) KQ(x3, 12)
    KQ(x4, 16) KQ(x5, 20) KQ(x6, 24) KQ(x7, 28)
#undef KQ
#undef KONE

    const float* Wf = Ww + 128;   // feat part: 3 float4 per kp, contiguous
    for (int kp = 0; kp < 128; ++kp){
      float f = sh[kp*65 + lane];
      const v2f* wp = (const v2f*)(Wf + kp*12);
      v2f fv; fv[0]=f; fv[1]=f;
      a01p += fv*wp[0];  a23p += fv*wp[1];
      a01s += fv*wp[2];  a23s += fv*wp[3];
      a01i += fv*wp[4];  a23i += fv*wp[5];
    }
    v2f sc2; sc2[0]=sc; sc2[1]=sc;
    v2f iv2; iv2[0]=iv; iv2[1]=iv;
    v2f a01 = a01p + sc2*a01s + iv2*a01i;
    v2f a23 = a23p + sc2*a23s + iv2*a23i;
    a01[0] += lin_b[l*32 + j0 + 0];
    a01[1] += lin_b[l*32 + j0 + 1];
    a23[0] += lin_b[l*32 + j0 + 2];
    a23[1] += lin_b[l*32 + j0 + 3];

    float v0r = fmaxf(a01[0], 0.f), v1r = fmaxf(a01[1], 0.f);
    float v2r = fmaxf(a23[0], 0.f), v3r = fmaxf(a23[1], 0.f);

    if (MODE==0 || MODE==1){
      if (n0 < NN){
        h_next[n0*32 + j0 + 0] = v0r;
        h_next[n0*32 + j0 + 1] = v1r;
        h_next[n0*32 + j0 + 2] = v2r;
        h_next[n0*32 + j0 + 3] = v3r;
      }
    }
    if (MODE==1){
      // ---- fused tdot (l=4): stage h5 rows, 64 threads do the 32-dot in
      // k_dot's exact ascending order -> bit-identical tdot ----
      __syncthreads();                    // all phase-2 sh reads complete
      sh[(j0+0)*65 + lane] = v0r;
      sh[(j0+1)*65 + lane] = v1r;
      sh[(j0+2)*65 + lane] = v2r;
      sh[(j0+3)*65 + lane] = v3r;
      __syncthreads();
      if (tid < 64){
        const float* relr = rel6 + 5*32;
        float s = 0.f;
        #pragma unroll
        for (int d = 0; d < 32; ++d) s += sh[d*65 + tid] * relr[d];
        if (base + tid < NN) tdot_out[base + tid] = s;
      }
    } else if (MODE==2){
      // ---- fused final MLP (l=5): h6 never leaves the block ----
      __syncthreads();                    // all phase-2 sh reads complete
      sh[(j0+0)*65 + lane] = v0r;         // stage h6 rows 0..31 (65-stride)
      sh[(j0+1)*65 + lane] = v1r;
      sh[(j0+2)*65 + lane] = v2r;
      sh[(j0+3)*65 + lane] = v3r;
      __syncthreads();
      int node = tid & 63;
      int grp2 = __builtin_amdgcn_readfirstlane(tid >> 6);   // 0..7
      int jm = grp2*8;                    // wave-uniform -> W1 s_loads
      v2f b0, b1v, b2v, b3;
      b0[0]=qc[jm+0]; b0[1]=qc[jm+1]; b1v[0]=qc[jm+2]; b1v[1]=qc[jm+3];
      b2v[0]=qc[jm+4]; b2v[1]=qc[jm+5]; b3[0]=qc[jm+6]; b3[1]=qc[jm+7];
      for (int k = 0; k < 32; ++k){
        float xv = sh[k*65 + node];
        const v2f* wr = (const v2f*)(W1 + k*64 + jm);
        v2f xv2; xv2[0]=xv; xv2[1]=xv;
        b0 += xv2*wr[0]; b1v += xv2*wr[1]; b2v += xv2*wr[2]; b3 += xv2*wr[3];
      }
      float part = fmaxf(b0[0],0.f)*W2[jm+0] + fmaxf(b0[1],0.f)*W2[jm+1]
                 + fmaxf(b1v[0],0.f)*W2[jm+2] + fmaxf(b1v[1],0.f)*W2[jm+3]
                 + fmaxf(b2v[0],0.f)*W2[jm+4] + fmaxf(b2v[1],0.f)*W2[jm+5]
                 + fmaxf(b3[0],0.f)*W2[jm+6] + fmaxf(b3[1],0.f)*W2[jm+7];
      sh[2080 + node*9 + grp2] = part;    // past the 32 staged rows (2080)
      __syncthreads();
      if (tid < 64){
        float s = b2[0];
        #pragma unroll
        for (int g = 0; g < 8; ++g) s += sh[2080 + tid*9 + g];
        if (base + tid < NN) out_score[base + tid] = s;
      }
    }
  }
}

// ---------------- host launch ----------------
extern "C" void kernel_launch(void* const* d_in, const int* in_sizes, int n_in,
                              void* d_out, int out_size, void* d_ws, size_t ws_size,
                              hipStream_t stream){
  const int*   node_in  = (const int*)d_in[0];
  const int*   node_out = (const int*)d_in[1];
  const float* ew       = (const float*)d_in[2];
  const int*   hidx     = (const int*)d_in[3];
  const float* qw       = (const float*)d_in[4];
  const float* rel_W    = (const float*)d_in[5];
  const float* rel_b    = (const float*)d_in[6];
  const float* lin_W    = (const float*)d_in[7];
  const float* lin_b    = (const float*)d_in[8];
  const float* W1       = (const float*)d_in[9];
  const float* b1       = (const float*)d_in[10];
  const float* W2       = (const float*)d_in[11];
  const float* b2       = (const float*)d_in[12];
  float* out_score = (float*)d_out;
  float* out_pred  = out_score + NN;

  char* w = (char*)d_ws;
  size_t off = 0;
  auto take = [&](size_t bytes)->char*{
    char* p = w + off;
    off = (off + bytes + 255) & ~(size_t)255;
    return p;
  };
  size_t bucket_elems = (size_t)NN * BSTR;            // int2 entries
  int2*  csr      = (int2*)take(bucket_elems*8);
  // contiguous zero block: cursor | deg_w | logsum
  char*  zb       = take((size_t)NN*4 + (size_t)NN*4 + 256);
  int*   cursor   = (int*)zb;
  float* deg_w    = (float*)(cursor + NN);
  float* logsum   = (float*)(deg_w + NN);
  int zc = NN + NN + 64;

  float* rel6      = (float*)take(192*4);
  float* qc        = (float*)take(64*4);
  float* wcol      = (float*)take(32*4);
  float* Wt        = (float*)take((size_t)48*416*16);   // packed weights
  float* tdot      = (float*)take((size_t)NN*4);
  float* h_a       = (float*)take((size_t)NN*32*4);
  float* h_b       = (float*)take((size_t)NN*32*4);

  int nsb = (NN + 31) / 32;     // 1563 (k_sumw: 32 nodes/block)
  int nlb = (NN + 63) / 64;     // 782
  k_zero   <<<(zc+255)/256, 256, 0, stream>>>((float*)zb, zc);
  k_fillcsr<<<NPART*CPB, 256, 0, stream>>>(node_in, node_out, ew, cursor, csr);
  k_sumw   <<<nsb, 256, 0, stream>>>(csr, cursor, deg_w, logsum);
  k_prep2  <<<49, 448, 0, stream>>>(qw, rel_W, rel_b, W1, b1, lin_W,
                                    rel6, qc, wcol, Wt);

  // layer 0 (specialized, no h input)
  k_layer0<<<nlb, 512, 0, stream>>>(rel6, cursor, csr, hidx, Wt, lin_b,
                                    wcol, deg_w, logsum, h_a);

  float* hc = h_a;
  float* hn = h_b;
  for (int l = 1; l < 6; ++l){
    if (l == 5){
      k_layer<2><<<nlb, 512, 0, stream>>>(hc, rel6, cursor, csr, hidx, tdot,
                                          Wt, lin_b, deg_w, logsum,
                                          hn, out_pred,
                                          qc, W1, W2, b2, out_score, tdot, l);
    } else if (l == 4){
      k_layer<1><<<nlb, 512, 0, stream>>>(hc, rel6, cursor, csr, hidx, tdot,
                                          Wt, lin_b, deg_w, logsum,
                                          hn, out_pred,
                                          qc, W1, W2, b2, out_score, tdot, l);
    } else {
      k_layer<0><<<nlb, 512, 0, stream>>>(hc, rel6, cursor, csr, hidx, tdot,
                                          Wt, lin_b, deg_w, logsum,
                                          hn, out_pred,
                                          qc, W1, W2, b2, out_score, tdot, l);
    }
    float* t1 = hc; hc = hn; hn = t1;
  }
}